// Round 1
// baseline (475.430 us; speedup 1.0000x reference)
//
#include <hip/hip_runtime.h>
#include <stdint.h>

#define BB 2
#define SS 4096
#define DD 768
#define HH 12
#define HDD 64
#define WW 256
#define GG 128
#define NBB 16

typedef __attribute__((ext_vector_type(4))) float f32x4;
typedef __attribute__((ext_vector_type(8))) short bf16x8;
typedef __attribute__((ext_vector_type(4))) short s16x4;
typedef __attribute__((ext_vector_type(4))) unsigned short u16x4;

__device__ __forceinline__ unsigned short f2bf(float x) {
  union { float f; unsigned int u; } v; v.f = x;
  return (unsigned short)((v.u + 0x7fffu + ((v.u >> 16) & 1u)) >> 16);
}

__device__ __forceinline__ void async16(void* lds, const void* g) {
  __builtin_amdgcn_global_load_lds(
      (const __attribute__((address_space(1))) unsigned int*)g,
      (__attribute__((address_space(3))) unsigned int*)lds, 16, 0, 0);
}

__device__ __forceinline__ uint32_t lds_b(const void* p) {
  return (uint32_t)(uintptr_t)(__attribute__((address_space(3))) const void*)p;
}

__device__ __forceinline__ s16x4 tr_read(uint32_t addr) {
  s16x4 d;
  asm volatile("ds_read_b64_tr_b16 %0, %1" : "=v"(d) : "v"(addr) : "memory");
  return d;
}

// ---------------- fp32 -> bf16 convert (x) ----------------
__global__ __launch_bounds__(256) void k_cvt(const float* __restrict__ x,
                                             unsigned short* __restrict__ o, int n4) {
  int i = blockIdx.x * 256 + threadIdx.x;
  if (i >= n4) return;
  f32x4 v = ((const f32x4*)x)[i];
  u16x4 r;
  r[0] = f2bf(v[0]); r[1] = f2bf(v[1]); r[2] = f2bf(v[2]); r[3] = f2bf(v[3]);
  ((u16x4*)o)[i] = r;
}

// ---------------- weight transpose + convert: Wt[n][k] = bf16(W[k][n]) ----------------
struct WArgs {
  const float* s[7];
  unsigned short* d[7];
};
__global__ __launch_bounds__(256) void k_tw(WArgs a) {
  __shared__ float t[64][65];
  const float* src = a.s[blockIdx.z];
  unsigned short* dst = a.d[blockIdx.z];
  int n0 = blockIdx.x * 64, k0 = blockIdx.y * 64;
#pragma unroll
  for (int it = 0; it < 16; ++it) {
    int idx = it * 256 + threadIdx.x;
    int r = idx >> 6, c = idx & 63;
    t[r][c] = src[(size_t)(k0 + r) * DD + n0 + c];
  }
  __syncthreads();
#pragma unroll
  for (int it = 0; it < 16; ++it) {
    int idx = it * 256 + threadIdx.x;
    int r = idx >> 6, c = idx & 63;
    dst[(size_t)(n0 + r) * DD + k0 + c] = f2bf(t[c][r]);
  }
}

// ---------------- GEMM: C = A(bf16, MxK) @ Wt^T(bf16, NxK) + bias ----------------
// OMODE 0: fused 5-projection, heads layout out, grid (M/128, 5*6)
// OMODE 1: qg (M=256, row-remapped input), qg layout out, grid (2, 6)
// OMODE 2: out-proj: fp32 Y = A@Wo + bo + resid, grid (64, 6)
template <int OMODE>
__global__ __launch_bounds__(256) void k_gemm(
    const unsigned short* __restrict__ A, const unsigned short* __restrict__ Wt,
    const float* __restrict__ b0, const float* __restrict__ b1,
    const float* __restrict__ b2, const float* __restrict__ b3,
    const float* __restrict__ b4, unsigned short* __restrict__ outH,
    float* __restrict__ outY, const float* __restrict__ resid) {
  const int bm = blockIdx.x;
  int bn, p;
  if (OMODE == 0) { p = blockIdx.y / 6; bn = blockIdx.y % 6; }
  else { p = 0; bn = blockIdx.y; }
  const float* bias = b0;
  if (OMODE == 0) bias = (p == 0) ? b0 : (p == 1) ? b1 : (p == 2) ? b2 : (p == 3) ? b3 : b4;
  const float scale = (OMODE == 1 || (OMODE == 0 && p == 0)) ? 0.125f : 1.0f;

  __shared__ unsigned short Asm_[128 * 64];
  __shared__ unsigned short Bsm_[128 * 64];
  const int tid = threadIdx.x;
  const int l = tid & 63, w = tid >> 6;
  const int wr = w >> 1, wc = w & 1;
  const int g = l >> 4, ln = l & 15;
  const int l3 = l >> 3, l7 = l & 7;
  const int slotsrc = l7 ^ l3;

  f32x4 zf = {0.f, 0.f, 0.f, 0.f};
  f32x4 acc[4][4];
#pragma unroll
  for (int i = 0; i < 4; ++i)
#pragma unroll
    for (int j = 0; j < 4; ++j) acc[i][j] = zf;

  const int wtrow0 = (OMODE == 0 ? p * DD : 0) + bn * 128;

  for (int kt = 0; kt < 12; ++kt) {
#pragma unroll
    for (int i = 0; i < 4; ++i) {
      int u = i * 4 + w;
      int row = u * 8 + l3;
      int ar = bm * 128 + row;
      if (OMODE == 1) ar = ((ar >> 7) << 12) + (ar & 127);
      async16(&Asm_[u * 512], A + (size_t)ar * DD + kt * 64 + slotsrc * 8);
      async16(&Bsm_[u * 512], Wt + (size_t)(wtrow0 + row) * DD + kt * 64 + slotsrc * 8);
    }
    __syncthreads();
#pragma unroll
    for (int kc = 0; kc < 2; ++kc) {
      bf16x8 af[4], bfr[4];
#pragma unroll
      for (int t = 0; t < 4; ++t) {
        int arow = wr * 64 + t * 16 + ln;
        af[t] = *(const bf16x8*)&Asm_[arow * 64 + (((kc * 4 + g) ^ (arow & 7)) << 3)];
        int brow = wc * 64 + t * 16 + ln;
        bfr[t] = *(const bf16x8*)&Bsm_[brow * 64 + (((kc * 4 + g) ^ (brow & 7)) << 3)];
      }
#pragma unroll
      for (int ti = 0; ti < 4; ++ti)
#pragma unroll
        for (int tj = 0; tj < 4; ++tj)
          acc[ti][tj] = __builtin_amdgcn_mfma_f32_16x16x32_bf16(af[ti], bfr[tj], acc[ti][tj], 0, 0, 0);
    }
    __syncthreads();
  }

#pragma unroll
  for (int tj = 0; tj < 4; ++tj) {
    int nl = bn * 128 + wc * 64 + tj * 16 + ln;  // 0..767
    float bv = bias[nl];
#pragma unroll
    for (int ti = 0; ti < 4; ++ti) {
#pragma unroll
      for (int r = 0; r < 4; ++r) {
        int m = bm * 128 + wr * 64 + ti * 16 + g * 4 + r;
        float val = acc[ti][tj][r] + bv;
        if (OMODE == 2) {
          outY[(size_t)m * DD + nl] = val + resid[(size_t)m * DD + nl];
        } else if (OMODE == 0) {
          val *= scale;
          int b = m >> 12, s = m & 4095, h = nl >> 6, d = nl & 63;
          outH[(size_t)p * (BB * HH * SS * HDD) +
               (((size_t)(b * HH + h) * SS + s) * HDD) + d] = f2bf(val);
        } else {
          val *= scale;
          int b = m >> 7, gi = m & 127, h = nl >> 6, d = nl & 63;
          outH[(((size_t)(b * HH + h) * GG + gi) * HDD) + d] = f2bf(val);
        }
      }
    }
  }
}

// ---------------- attention ----------------
// MODE 0: banded+global-keys, 1 block per (b,h,n-block of 256 q), 512 thr
// MODE 1: full attention for 128 global queries, 1 block per (b,h), 512 thr
template <int MODE>
__global__ __launch_bounds__(512) void k_attn(
    const unsigned short* __restrict__ qbuf, const unsigned short* __restrict__ kbuf,
    const unsigned short* __restrict__ vbuf, unsigned short* __restrict__ ctx) {
  constexpr int TQ = (MODE == 0) ? 2 : 1;
  constexpr int NC = (MODE == 0) ? 14 : 64;

  __shared__ unsigned short Ksm[64 * 64];
  __shared__ unsigned short Vsm[64 * 64];    // subtiled [key/4][d/16][4][16]
  __shared__ unsigned short Psm[8 * 32 * 64];

  const int tid = threadIdx.x;
  const int l = tid & 63, w = tid >> 6;
  const int g = l >> 4, ln = l & 15;

  int b, h, n;
  if (MODE == 0) { n = blockIdx.x & 15; h = (blockIdx.x >> 4) % 12; b = blockIdx.x / (16 * 12); }
  else { n = 0; h = blockIdx.x % 12; b = blockIdx.x / 12; }
  (void)n;

  const size_t bh = (size_t)(b * HH + h);
  const unsigned short* qp = qbuf + bh * (size_t)((MODE == 0) ? SS * HDD : GG * HDD);
  const unsigned short* kp = kbuf + bh * (size_t)(SS * HDD);
  const unsigned short* vp = vbuf + bh * (size_t)(SS * HDD);

  const int qrow0 = (MODE == 0) ? (n * 256 + w * 32) : (w * 16);

  bf16x8 qf[TQ][2];
#pragma unroll
  for (int t = 0; t < TQ; ++t)
#pragma unroll
    for (int kc = 0; kc < 2; ++kc)
      qf[t][kc] = *(const bf16x8*)&qp[(size_t)(qrow0 + t * 16 + ln) * HDD + kc * 32 + g * 8];

  f32x4 zf = {0.f, 0.f, 0.f, 0.f};
  f32x4 o[TQ][4];
  float mrun[TQ][4], lrun[TQ][4];
#pragma unroll
  for (int t = 0; t < TQ; ++t) {
#pragma unroll
    for (int dj = 0; dj < 4; ++dj) o[t][dj] = zf;
#pragma unroll
    for (int r = 0; r < 4; ++r) { mrun[t][r] = -1e30f; lrun[t][r] = 0.f; }
  }

  const uint32_t vbase = lds_b(Vsm);

  for (int c = 0; c < NC; ++c) {
    int kbase;
    bool isBand = false;
    if (MODE == 0) {
      if (c < 2) kbase = c * 64;
      else {
        isBand = true;
        kbase = n * 256 - 256 + (c - 2) * 64;
        if (kbase + 63 < GG || kbase >= SS) continue;  // block-uniform skip
      }
    } else kbase = c * 64;

    __syncthreads();
    {  // stage K: row-major [64][64], slot ^= row&7, via global_load_lds
      int row = w * 8 + (l >> 3);
      int srcrow = kbase + row;
      srcrow = srcrow < 0 ? 0 : (srcrow > SS - 1 ? SS - 1 : srcrow);
      async16(&Ksm[w * 512], kp + (size_t)srcrow * HDD + (size_t)(((l & 7) ^ (l >> 3)) << 3));
    }
    {  // stage V into subtiled layout (reg->lds, one b128 write per thread)
      int key = tid >> 3;
      int dc = tid & 7;
      int srcrow = kbase + key;
      srcrow = srcrow < 0 ? 0 : (srcrow > SS - 1 ? SS - 1 : srcrow);
      bf16x8 vv = *(const bf16x8*)&vp[(size_t)srcrow * HDD + dc * 8];
      int off = ((key >> 2) << 8) | ((dc >> 1) << 6) | ((key & 3) << 4) | ((dc & 1) << 3);
      *(bf16x8*)&Vsm[off] = vv;
    }
    __syncthreads();

    // ---- QK^T ----
    f32x4 sc[TQ][4];
#pragma unroll
    for (int t = 0; t < TQ; ++t)
#pragma unroll
      for (int cj = 0; cj < 4; ++cj) sc[t][cj] = zf;
#pragma unroll
    for (int kc = 0; kc < 2; ++kc) {
      bf16x8 kf[4];
#pragma unroll
      for (int cj = 0; cj < 4; ++cj) {
        int key = cj * 16 + ln;
        kf[cj] = *(const bf16x8*)&Ksm[key * 64 + (((kc * 4 + g) ^ (key & 7)) << 3)];
      }
#pragma unroll
      for (int t = 0; t < TQ; ++t)
#pragma unroll
        for (int cj = 0; cj < 4; ++cj)
          sc[t][cj] = __builtin_amdgcn_mfma_f32_16x16x32_bf16(qf[t][kc], kf[cj], sc[t][cj], 0, 0, 0);
    }

    // ---- mask (band chunks only) ----
    if (MODE == 0 && isBand) {
#pragma unroll
      for (int t = 0; t < TQ; ++t)
#pragma unroll
        for (int cj = 0; cj < 4; ++cj)
#pragma unroll
          for (int r = 0; r < 4; ++r) {
            int qi = w * 32 + t * 16 + g * 4 + r;
            int keyloc = cj * 16 + ln;
            int kk = (c - 2) * 64 + keyloc;
            int kpos = kbase + keyloc;
            bool valid = (kk >= qi) & (kk <= qi + 2 * WW) & (kpos >= GG) & (kpos < SS);
            if (!valid) sc[t][cj][r] = -1e9f;
          }
    }

    // ---- online softmax ----
    float alpha[TQ][4];
#pragma unroll
    for (int t = 0; t < TQ; ++t)
#pragma unroll
      for (int r = 0; r < 4; ++r) {
        float m4 = fmaxf(fmaxf(sc[t][0][r], sc[t][1][r]), fmaxf(sc[t][2][r], sc[t][3][r]));
#pragma unroll
        for (int d = 1; d < 16; d <<= 1) m4 = fmaxf(m4, __shfl_xor(m4, d, 64));
        float mnew = fmaxf(mrun[t][r], m4);
        float al = __expf(mrun[t][r] - mnew);
        mrun[t][r] = mnew;
        float rs = 0.f;
#pragma unroll
        for (int cj = 0; cj < 4; ++cj) {
          float pv = __expf(sc[t][cj][r] - mnew);
          sc[t][cj][r] = pv;
          rs += pv;
        }
#pragma unroll
        for (int d = 1; d < 16; d <<= 1) rs += __shfl_xor(rs, d, 64);
        lrun[t][r] = lrun[t][r] * al + rs;
        alpha[t][r] = al;
      }

#pragma unroll
    for (int t = 0; t < TQ; ++t)
#pragma unroll
      for (int dj = 0; dj < 4; ++dj)
#pragma unroll
        for (int r = 0; r < 4; ++r) o[t][dj][r] *= alpha[t][r];

    // ---- P -> LDS (bf16, swizzled) ----
#pragma unroll
    for (int t = 0; t < TQ; ++t)
#pragma unroll
      for (int cj = 0; cj < 4; ++cj)
#pragma unroll
        for (int r = 0; r < 4; ++r) {
          int prow = t * 16 + g * 4 + r;
          int pcol = cj * 16 + ln;
          Psm[w * 2048 + prow * 64 + ((((pcol >> 3) ^ (prow & 7)) << 3)) + (pcol & 7)] =
              f2bf(sc[t][cj][r]);
        }

    // ---- PV ----
#pragma unroll
    for (int kc = 0; kc < 2; ++kc) {
      s16x4 vlo[4], vhi[4];
#pragma unroll
      for (int dj = 0; dj < 4; ++dj) {
        uint32_t a = vbase + (uint32_t)(((kc * 8 + g * 2) * 256 + dj * 64 + ln) * 2);
        vlo[dj] = tr_read(a);
        vhi[dj] = tr_read(a + 512);
      }
      bf16x8 pa[TQ];
#pragma unroll
      for (int t = 0; t < TQ; ++t) {
        int prow = t * 16 + ln;
        pa[t] = *(const bf16x8*)&Psm[w * 2048 + prow * 64 + (((kc * 4 + g) ^ (prow & 7)) << 3)];
      }
      asm volatile("s_waitcnt lgkmcnt(0)" ::: "memory");
      __builtin_amdgcn_sched_barrier(0);
#pragma unroll
      for (int dj = 0; dj < 4; ++dj) {
        bf16x8 vf = __builtin_shufflevector(vlo[dj], vhi[dj], 0, 1, 2, 3, 4, 5, 6, 7);
#pragma unroll
        for (int t = 0; t < TQ; ++t)
          o[t][dj] = __builtin_amdgcn_mfma_f32_16x16x32_bf16(pa[t], vf, o[t][dj], 0, 0, 0);
      }
    }
  }

  // ---- epilogue: O/l -> ctx[b][s][h*64+d] ----
#pragma unroll
  for (int t = 0; t < TQ; ++t)
#pragma unroll
    for (int r = 0; r < 4; ++r) {
      float inv = 1.f / lrun[t][r];
      int spos = qrow0 + t * 16 + g * 4 + r;
#pragma unroll
      for (int dj = 0; dj < 4; ++dj) {
        int dcol = dj * 16 + ln;
        ctx[((size_t)b * SS + spos) * DD + h * HDD + dcol] = f2bf(o[t][dj][r] * inv);
      }
    }
}

// ---------------- layernorm ----------------
__global__ __launch_bounds__(256) void k_ln(const float* __restrict__ Y,
                                            const float* __restrict__ gam,
                                            const float* __restrict__ bet,
                                            float* __restrict__ outp) {
  const int row = blockIdx.x;
  const float* y = Y + (size_t)row * DD;
  float v0 = y[threadIdx.x], v1 = y[threadIdx.x + 256], v2 = y[threadIdx.x + 512];
  float s = v0 + v1 + v2, s2 = v0 * v0 + v1 * v1 + v2 * v2;
#pragma unroll
  for (int d = 1; d < 64; d <<= 1) { s += __shfl_xor(s, d, 64); s2 += __shfl_xor(s2, d, 64); }
  __shared__ float r1[4], r2[4];
  int w = threadIdx.x >> 6, l = threadIdx.x & 63;
  if (l == 0) { r1[w] = s; r2[w] = s2; }
  __syncthreads();
  s = r1[0] + r1[1] + r1[2] + r1[3];
  s2 = r2[0] + r2[1] + r2[2] + r2[3];
  float mu = s * (1.f / 768.f);
  float var = s2 * (1.f / 768.f) - mu * mu;
  float rstd = rsqrtf(var + 1e-5f);
  float* op = outp + (size_t)row * DD;
  op[threadIdx.x] = (v0 - mu) * rstd * gam[threadIdx.x] + bet[threadIdx.x];
  op[threadIdx.x + 256] = (v1 - mu) * rstd * gam[threadIdx.x + 256] + bet[threadIdx.x + 256];
  op[threadIdx.x + 512] = (v2 - mu) * rstd * gam[threadIdx.x + 512] + bet[threadIdx.x + 512];
}

// ---------------- launch ----------------
extern "C" void kernel_launch(void* const* d_in, const int* in_sizes, int n_in,
                              void* d_out, int out_size, void* d_ws, size_t ws_size,
                              hipStream_t stream) {
  const float* hidden = (const float*)d_in[0];
  const float* Wq = (const float*)d_in[3];  const float* bq = (const float*)d_in[4];
  const float* Wk = (const float*)d_in[5];  const float* bk = (const float*)d_in[6];
  const float* Wv = (const float*)d_in[7];  const float* bv = (const float*)d_in[8];
  const float* Wqg = (const float*)d_in[9]; const float* bqg = (const float*)d_in[10];
  const float* Wkg = (const float*)d_in[11]; const float* bkg = (const float*)d_in[12];
  const float* Wvg = (const float*)d_in[13]; const float* bvg = (const float*)d_in[14];
  const float* Wo = (const float*)d_in[15]; const float* bo = (const float*)d_in[16];
  const float* gam = (const float*)d_in[17]; const float* bet = (const float*)d_in[18];

  char* ws = (char*)d_ws;
  const size_t SZH = (size_t)BB * HH * SS * HDD;  // 6,291,456 elems per proj
  unsigned short* xb = (unsigned short*)(ws);                                   // 12.58 MB; later: ctx
  unsigned short* Wt5 = (unsigned short*)(ws + 12582912);                       // 5.90 MB
  unsigned short* Wtqg = (unsigned short*)(ws + 12582912 + 5898240);            // 1.18 MB
  unsigned short* Wto = (unsigned short*)(ws + 12582912 + 5898240 + 1179648);   // 1.18 MB
  unsigned short* qkv = (unsigned short*)(ws + 20840448);                       // 5 x 12.58 MB
  unsigned short* qg = (unsigned short*)(ws + 20840448 + 62914560);             // 0.39 MB
  unsigned short* ctx = xb;      // alias: xb dead after qg GEMM
  float* Y = (float*)qkv;        // alias: q/k slots dead after attention

  k_cvt<<<dim3((BB * SS * DD / 4 + 255) / 256), dim3(256), 0, stream>>>(hidden, xb, BB * SS * DD / 4);

  WArgs wa;
  wa.s[0] = Wq; wa.s[1] = Wk; wa.s[2] = Wv; wa.s[3] = Wkg; wa.s[4] = Wvg; wa.s[5] = Wqg; wa.s[6] = Wo;
  wa.d[0] = Wt5; wa.d[1] = Wt5 + 589824; wa.d[2] = Wt5 + 2 * 589824;
  wa.d[3] = Wt5 + 3 * 589824; wa.d[4] = Wt5 + 4 * 589824;
  wa.d[5] = Wtqg; wa.d[6] = Wto;
  k_tw<<<dim3(12, 12, 7), dim3(256), 0, stream>>>(wa);

  k_gemm<0><<<dim3(64, 30), dim3(256), 0, stream>>>(xb, Wt5, bq, bk, bv, bkg, bvg, qkv, nullptr, nullptr);
  k_gemm<1><<<dim3(2, 6), dim3(256), 0, stream>>>(xb, Wtqg, bqg, nullptr, nullptr, nullptr, nullptr, qg, nullptr, nullptr);

  k_attn<0><<<dim3(BB * HH * NBB), dim3(512), 0, stream>>>(qkv, qkv + SZH, qkv + 2 * SZH, ctx);
  k_attn<1><<<dim3(BB * HH), dim3(512), 0, stream>>>(qg, qkv + 3 * SZH, qkv + 4 * SZH, ctx);

  k_gemm<2><<<dim3(64, 6), dim3(256), 0, stream>>>(ctx, Wto, bo, nullptr, nullptr, nullptr, nullptr, nullptr, Y, hidden);

  k_ln<<<dim3(BB * SS), dim3(256), 0, stream>>>(Y, gam, bet, (float*)d_out);
}

// Round 2
// 372.524 us; speedup vs baseline: 1.2762x; 1.2762x over previous
//
#include <hip/hip_runtime.h>
#include <stdint.h>

#define BB 2
#define SS 4096
#define DD 768
#define HH 12
#define HDD 64
#define WW 256
#define GG 128
#define NBB 16
#define NSPLIT 16

typedef __attribute__((ext_vector_type(4))) float f32x4;
typedef __attribute__((ext_vector_type(8))) short bf16x8;
typedef __attribute__((ext_vector_type(4))) short s16x4;
typedef __attribute__((ext_vector_type(4))) unsigned short u16x4;

__device__ __forceinline__ unsigned short f2bf(float x) {
  union { float f; unsigned int u; } v; v.f = x;
  return (unsigned short)((v.u + 0x7fffu + ((v.u >> 16) & 1u)) >> 16);
}

__device__ __forceinline__ void async16(void* lds, const void* g) {
  __builtin_amdgcn_global_load_lds(
      (const __attribute__((address_space(1))) unsigned int*)g,
      (__attribute__((address_space(3))) unsigned int*)lds, 16, 0, 0);
}

__device__ __forceinline__ uint32_t lds_b(const void* p) {
  return (uint32_t)(uintptr_t)(__attribute__((address_space(3))) const void*)p;
}

__device__ __forceinline__ s16x4 tr_read(uint32_t addr) {
  s16x4 d;
  asm volatile("ds_read_b64_tr_b16 %0, %1" : "=v"(d) : "v"(addr) : "memory");
  return d;
}

// ---------------- fp32 -> bf16 convert (x) ----------------
__global__ __launch_bounds__(256) void k_cvt(const float* __restrict__ x,
                                             unsigned short* __restrict__ o, int n4) {
  int i = blockIdx.x * 256 + threadIdx.x;
  if (i >= n4) return;
  f32x4 v = ((const f32x4*)x)[i];
  u16x4 r;
  r[0] = f2bf(v[0]); r[1] = f2bf(v[1]); r[2] = f2bf(v[2]); r[3] = f2bf(v[3]);
  ((u16x4*)o)[i] = r;
}

// ---------------- weight transpose + convert: Wt[n][k] = bf16(W[k][n]) ----------------
struct WArgs {
  const float* s[7];
  unsigned short* d[7];
};
__global__ __launch_bounds__(256) void k_tw(WArgs a) {
  __shared__ float t[64][65];
  const float* src = a.s[blockIdx.z];
  unsigned short* dst = a.d[blockIdx.z];
  int n0 = blockIdx.x * 64, k0 = blockIdx.y * 64;
#pragma unroll
  for (int it = 0; it < 16; ++it) {
    int idx = it * 256 + threadIdx.x;
    int r = idx >> 6, c = idx & 63;
    t[r][c] = src[(size_t)(k0 + r) * DD + n0 + c];
  }
  __syncthreads();
#pragma unroll
  for (int it = 0; it < 16; ++it) {
    int idx = it * 256 + threadIdx.x;
    int r = idx >> 6, c = idx & 63;
    dst[(size_t)(n0 + r) * DD + k0 + c] = f2bf(t[c][r]);
  }
}

// ---------------- GEMM: C = A(bf16, MxK) @ Wt^T(bf16, NxK) + bias ----------------
template <int OMODE>
__global__ __launch_bounds__(256) void k_gemm(
    const unsigned short* __restrict__ A, const unsigned short* __restrict__ Wt,
    const float* __restrict__ b0, const float* __restrict__ b1,
    const float* __restrict__ b2, const float* __restrict__ b3,
    const float* __restrict__ b4, unsigned short* __restrict__ outH,
    float* __restrict__ outY, const float* __restrict__ resid) {
  const int bm = blockIdx.x;
  int bn, p;
  if (OMODE == 0) { p = blockIdx.y / 6; bn = blockIdx.y % 6; }
  else { p = 0; bn = blockIdx.y; }
  const float* bias = b0;
  if (OMODE == 0) bias = (p == 0) ? b0 : (p == 1) ? b1 : (p == 2) ? b2 : (p == 3) ? b3 : b4;
  const float scale = (OMODE == 1 || (OMODE == 0 && p == 0)) ? 0.125f : 1.0f;

  __shared__ unsigned short Asm_[128 * 64];
  __shared__ unsigned short Bsm_[128 * 64];
  const int tid = threadIdx.x;
  const int l = tid & 63, w = tid >> 6;
  const int wr = w >> 1, wc = w & 1;
  const int g = l >> 4, ln = l & 15;
  const int l3 = l >> 3, l7 = l & 7;
  const int slotsrc = l7 ^ l3;

  f32x4 zf = {0.f, 0.f, 0.f, 0.f};
  f32x4 acc[4][4];
#pragma unroll
  for (int i = 0; i < 4; ++i)
#pragma unroll
    for (int j = 0; j < 4; ++j) acc[i][j] = zf;

  const int wtrow0 = (OMODE == 0 ? p * DD : 0) + bn * 128;

  for (int kt = 0; kt < 12; ++kt) {
#pragma unroll
    for (int i = 0; i < 4; ++i) {
      int u = i * 4 + w;
      int row = u * 8 + l3;
      int ar = bm * 128 + row;
      if (OMODE == 1) ar = ((ar >> 7) << 12) + (ar & 127);
      async16(&Asm_[u * 512], A + (size_t)ar * DD + kt * 64 + slotsrc * 8);
      async16(&Bsm_[u * 512], Wt + (size_t)(wtrow0 + row) * DD + kt * 64 + slotsrc * 8);
    }
    __syncthreads();
#pragma unroll
    for (int kc = 0; kc < 2; ++kc) {
      bf16x8 af[4], bfr[4];
#pragma unroll
      for (int t = 0; t < 4; ++t) {
        int arow = wr * 64 + t * 16 + ln;
        af[t] = *(const bf16x8*)&Asm_[arow * 64 + (((kc * 4 + g) ^ (arow & 7)) << 3)];
        int brow = wc * 64 + t * 16 + ln;
        bfr[t] = *(const bf16x8*)&Bsm_[brow * 64 + (((kc * 4 + g) ^ (brow & 7)) << 3)];
      }
#pragma unroll
      for (int ti = 0; ti < 4; ++ti)
#pragma unroll
        for (int tj = 0; tj < 4; ++tj)
          acc[ti][tj] = __builtin_amdgcn_mfma_f32_16x16x32_bf16(af[ti], bfr[tj], acc[ti][tj], 0, 0, 0);
    }
    __syncthreads();
  }

#pragma unroll
  for (int tj = 0; tj < 4; ++tj) {
    int nl = bn * 128 + wc * 64 + tj * 16 + ln;  // 0..767
    float bv = bias[nl];
#pragma unroll
    for (int ti = 0; ti < 4; ++ti) {
#pragma unroll
      for (int r = 0; r < 4; ++r) {
        int m = bm * 128 + wr * 64 + ti * 16 + g * 4 + r;
        float val = acc[ti][tj][r] + bv;
        if (OMODE == 2) {
          outY[(size_t)m * DD + nl] = val + resid[(size_t)m * DD + nl];
        } else if (OMODE == 0) {
          val *= scale;
          int b = m >> 12, s = m & 4095, h = nl >> 6, d = nl & 63;
          outH[(size_t)p * (BB * HH * SS * HDD) +
               (((size_t)(b * HH + h) * SS + s) * HDD) + d] = f2bf(val);
        } else {
          val *= scale;
          int b = m >> 7, gi = m & 127, h = nl >> 6, d = nl & 63;
          outH[(((size_t)(b * HH + h) * GG + gi) * HDD) + d] = f2bf(val);
        }
      }
    }
  }
}

// ---------------- attention ----------------
// MODE 0: banded + global-keys, 1 block per (b,h,q-block of 256), 512 thr, out -> ctx
// MODE 1: global-query full attention, SPLIT-K: 1 block per (b,h,split of 256 keys),
//         partial O (f32, unnormalized) + (m,l) -> workspace
template <int MODE>
__global__ __launch_bounds__(512) void k_attn(
    const unsigned short* __restrict__ qbuf, const unsigned short* __restrict__ kbuf,
    const unsigned short* __restrict__ vbuf, unsigned short* __restrict__ ctx,
    float* __restrict__ Opart, float* __restrict__ mlp) {
  constexpr int TQ = (MODE == 0) ? 2 : 1;
  constexpr int MAXCH = (MODE == 0) ? 14 : 4;

  __shared__ unsigned short Ksm[2][64 * 64];
  __shared__ unsigned short Vsm[2][64 * 64];   // subtiled [key/4][d/16][4][16]
  __shared__ unsigned short Psm[8][16 * 64];   // per-wave P tile

  const int tid = threadIdx.x;
  const int l = tid & 63, w = tid >> 6;
  const int g = l >> 4, ln = l & 15;
  const int l3 = l >> 3, l7 = l & 7;

  int b, h, n, split;
  if (MODE == 0) {
    n = blockIdx.x & 15; h = (blockIdx.x >> 4) % 12; b = blockIdx.x / (16 * 12); split = 0;
  } else {
    split = blockIdx.x & 15; int bhid = blockIdx.x >> 4; h = bhid % 12; b = bhid / 12; n = 0;
  }

  const size_t bh = (size_t)(b * HH + h);
  const unsigned short* qp = qbuf + bh * (size_t)((MODE == 0) ? SS * HDD : GG * HDD);
  const unsigned short* kp = kbuf + bh * (size_t)(SS * HDD);
  const unsigned short* vp = vbuf + bh * (size_t)(SS * HDD);

  // uniform chunk list (no in-loop skipping -> clean pipeline)
  int kbs[MAXCH]; int nch = 0;
  if (MODE == 0) {
    kbs[nch++] = 0; kbs[nch++] = 64;
#pragma unroll
    for (int j = 0; j < 12; ++j) {
      int kb = n * 256 - 256 + j * 64;
      if (kb >= GG && kb < SS) kbs[nch++] = kb;
    }
  } else {
#pragma unroll
    for (int i = 0; i < 4; ++i) kbs[nch++] = (split * 4 + i) * 64;
  }

  const int qrow0 = (MODE == 0) ? (n * 256 + w * 32) : (w * 16);

  bf16x8 qf[TQ][2];
#pragma unroll
  for (int t = 0; t < TQ; ++t)
#pragma unroll
    for (int kc = 0; kc < 2; ++kc)
      qf[t][kc] = *(const bf16x8*)&qp[(size_t)(qrow0 + t * 16 + ln) * HDD + kc * 32 + g * 8];

  f32x4 zf = {0.f, 0.f, 0.f, 0.f};
  f32x4 o[TQ][4];
  float mrun[TQ][4], lrun[TQ][4];
#pragma unroll
  for (int t = 0; t < TQ; ++t) {
#pragma unroll
    for (int dj = 0; dj < 4; ++dj) o[t][dj] = zf;
#pragma unroll
    for (int r = 0; r < 4; ++r) { mrun[t][r] = -1e30f; lrun[t][r] = 0.f; }
  }

  const uint32_t vbase = lds_b(Vsm);
  const int vwoff = (((tid >> 3) >> 2) << 8) | (((tid & 7) >> 1) << 6) |
                    (((tid >> 3) & 3) << 4) | ((tid & 1) << 3);

  // prologue: stage chunk 0 into buf 0
  bf16x8 vv;
  {
    int kb = kbs[0];
    async16(&Ksm[0][w * 512], kp + (size_t)(kb + w * 8 + l3) * HDD + (size_t)((l7 ^ l3) << 3));
    vv = *(const bf16x8*)&vp[(size_t)(kb + (tid >> 3)) * HDD + (size_t)((tid & 7) << 3)];
  }
  int buf = 0;

  for (int ci = 0; ci < nch; ++ci) {
    const int kbase = kbs[ci];
    asm volatile("s_waitcnt vmcnt(0)" ::: "memory");   // K(cur) landed in LDS
    *(bf16x8*)&Vsm[buf][vwoff] = vv;                   // V(cur) reg -> LDS
    __syncthreads();

    bf16x8 vnext;
    if (ci + 1 < nch) {  // issue next-chunk stage; hides under compute
      int kb = kbs[ci + 1];
      async16(&Ksm[buf ^ 1][w * 512],
              kp + (size_t)(kb + w * 8 + l3) * HDD + (size_t)((l7 ^ l3) << 3));
      vnext = *(const bf16x8*)&vp[(size_t)(kb + (tid >> 3)) * HDD + (size_t)((tid & 7) << 3)];
    }

    // ---- QK^T ----
    f32x4 sc[TQ][4];
#pragma unroll
    for (int t = 0; t < TQ; ++t)
#pragma unroll
      for (int cj = 0; cj < 4; ++cj) sc[t][cj] = zf;
#pragma unroll
    for (int kc = 0; kc < 2; ++kc) {
      bf16x8 kf[4];
#pragma unroll
      for (int cj = 0; cj < 4; ++cj) {
        int key = cj * 16 + ln;
        kf[cj] = *(const bf16x8*)&Ksm[buf][key * 64 + (((kc * 4 + g) ^ (key & 7)) << 3)];
      }
#pragma unroll
      for (int t = 0; t < TQ; ++t)
#pragma unroll
        for (int cj = 0; cj < 4; ++cj)
          sc[t][cj] = __builtin_amdgcn_mfma_f32_16x16x32_bf16(qf[t][kc], kf[cj], sc[t][cj], 0, 0, 0);
    }

    // ---- band mask (band chunks have kbase >= GG; kpos bounds guaranteed valid) ----
    if (MODE == 0 && kbase >= GG) {
      const int koff = kbase - (n * 256 - 256);
#pragma unroll
      for (int t = 0; t < TQ; ++t)
#pragma unroll
        for (int cj = 0; cj < 4; ++cj) {
          int kk = koff + cj * 16 + ln;
#pragma unroll
          for (int r = 0; r < 4; ++r) {
            int qi = w * 32 + t * 16 + g * 4 + r;
            if (!(kk >= qi && kk <= qi + 2 * WW)) sc[t][cj][r] = -1e9f;
          }
        }
    }

    // ---- online softmax ----
    float alpha[TQ][4];
#pragma unroll
    for (int t = 0; t < TQ; ++t)
#pragma unroll
      for (int r = 0; r < 4; ++r) {
        float m4 = fmaxf(fmaxf(sc[t][0][r], sc[t][1][r]), fmaxf(sc[t][2][r], sc[t][3][r]));
#pragma unroll
        for (int d = 1; d < 16; d <<= 1) m4 = fmaxf(m4, __shfl_xor(m4, d, 64));
        float mnew = fmaxf(mrun[t][r], m4);
        float al = __expf(mrun[t][r] - mnew);
        mrun[t][r] = mnew;
        float rs = 0.f;
#pragma unroll
        for (int cj = 0; cj < 4; ++cj) {
          float pv = __expf(sc[t][cj][r] - mnew);
          sc[t][cj][r] = pv;
          rs += pv;
        }
#pragma unroll
        for (int d = 1; d < 16; d <<= 1) rs += __shfl_xor(rs, d, 64);
        lrun[t][r] = lrun[t][r] * al + rs;
        alpha[t][r] = al;
      }

#pragma unroll
    for (int t = 0; t < TQ; ++t)
#pragma unroll
      for (int dj = 0; dj < 4; ++dj)
#pragma unroll
        for (int r = 0; r < 4; ++r) o[t][dj][r] *= alpha[t][r];

    // ---- PV (per-wave Psm, t-loop reuse) ----
    const uint32_t vb = vbase + (uint32_t)(buf << 13);
#pragma unroll
    for (int t = 0; t < TQ; ++t) {
#pragma unroll
      for (int cj = 0; cj < 4; ++cj) {
        int pcol = cj * 16 + ln;
#pragma unroll
        for (int r = 0; r < 4; ++r) {
          int prow = g * 4 + r;
          Psm[w][prow * 64 + (((pcol >> 3) ^ (prow & 7)) << 3) + (pcol & 7)] =
              f2bf(sc[t][cj][r]);
        }
      }
#pragma unroll
      for (int kc = 0; kc < 2; ++kc) {
        s16x4 vlo[4], vhi[4];
#pragma unroll
        for (int dj = 0; dj < 4; ++dj) {
          uint32_t a = vb + (uint32_t)((((kc * 8 + g * 2) * 256) + dj * 64 + ln) * 2);
          vlo[dj] = tr_read(a);
          vhi[dj] = tr_read(a + 512);
        }
        bf16x8 pa = *(const bf16x8*)&Psm[w][ln * 64 + (((kc * 4 + g) ^ (ln & 7)) << 3)];
        asm volatile("s_waitcnt lgkmcnt(0)" ::: "memory");
        __builtin_amdgcn_sched_barrier(0);
#pragma unroll
        for (int dj = 0; dj < 4; ++dj) {
          bf16x8 vf = __builtin_shufflevector(vlo[dj], vhi[dj], 0, 1, 2, 3, 4, 5, 6, 7);
          o[t][dj] = __builtin_amdgcn_mfma_f32_16x16x32_bf16(pa, vf, o[t][dj], 0, 0, 0);
        }
      }
    }

    vv = vnext;
    buf ^= 1;
  }

  // ---- epilogue ----
  if (MODE == 0) {
#pragma unroll
    for (int t = 0; t < TQ; ++t)
#pragma unroll
      for (int r = 0; r < 4; ++r) {
        float inv = 1.f / lrun[t][r];
        int spos = qrow0 + t * 16 + g * 4 + r;
#pragma unroll
        for (int dj = 0; dj < 4; ++dj) {
          int dcol = dj * 16 + ln;
          ctx[((size_t)b * SS + spos) * DD + h * HDD + dcol] = f2bf(o[t][dj][r] * inv);
        }
      }
  } else {
#pragma unroll
    for (int r = 0; r < 4; ++r) {
      int q = w * 16 + g * 4 + r;
      size_t base = (((bh * NSPLIT + split) * GG) + q) * (size_t)HDD;
#pragma unroll
      for (int dj = 0; dj < 4; ++dj) Opart[base + dj * 16 + ln] = o[0][dj][r];
      if (ln == 0) {
        size_t mb = (((bh * NSPLIT + split) * GG) + q) * 2;
        mlp[mb] = mrun[0][r];
        mlp[mb + 1] = lrun[0][r];
      }
    }
  }
}

// ---------------- split-K reduce for global queries ----------------
__global__ __launch_bounds__(256) void k_red(const float* __restrict__ Opart,
                                             const float* __restrict__ mlp,
                                             unsigned short* __restrict__ ctx) {
  int wid = blockIdx.x * 4 + (threadIdx.x >> 6);  // 0..3071 = bh*128 + q
  int d = threadIdx.x & 63;
  int bh = wid >> 7, q = wid & 127;
  int b = bh / HH, h = bh % HH;

  float mmax = -1e30f;
#pragma unroll
  for (int s = 0; s < NSPLIT; ++s)
    mmax = fmaxf(mmax, mlp[(((size_t)bh * NSPLIT + s) * GG + q) * 2]);
  float acc = 0.f, denom = 0.f;
#pragma unroll
  for (int s = 0; s < NSPLIT; ++s) {
    size_t mb = (((size_t)bh * NSPLIT + s) * GG + q) * 2;
    float wgt = __expf(mlp[mb] - mmax);
    denom += wgt * mlp[mb + 1];
    acc += wgt * Opart[(((size_t)bh * NSPLIT + s) * GG + q) * HDD + d];
  }
  ctx[((size_t)b * SS + q) * DD + h * HDD + d] = f2bf(acc / denom);
}

// ---------------- layernorm ----------------
__global__ __launch_bounds__(256) void k_ln(const float* __restrict__ Y,
                                            const float* __restrict__ gam,
                                            const float* __restrict__ bet,
                                            float* __restrict__ outp) {
  const int row = blockIdx.x;
  const float* y = Y + (size_t)row * DD;
  float v0 = y[threadIdx.x], v1 = y[threadIdx.x + 256], v2 = y[threadIdx.x + 512];
  float s = v0 + v1 + v2, s2 = v0 * v0 + v1 * v1 + v2 * v2;
#pragma unroll
  for (int d = 1; d < 64; d <<= 1) { s += __shfl_xor(s, d, 64); s2 += __shfl_xor(s2, d, 64); }
  __shared__ float r1[4], r2[4];
  int w = threadIdx.x >> 6, l = threadIdx.x & 63;
  if (l == 0) { r1[w] = s; r2[w] = s2; }
  __syncthreads();
  s = r1[0] + r1[1] + r1[2] + r1[3];
  s2 = r2[0] + r2[1] + r2[2] + r2[3];
  float mu = s * (1.f / 768.f);
  float var = s2 * (1.f / 768.f) - mu * mu;
  float rstd = rsqrtf(var + 1e-5f);
  float* op = outp + (size_t)row * DD;
  op[threadIdx.x] = (v0 - mu) * rstd * gam[threadIdx.x] + bet[threadIdx.x];
  op[threadIdx.x + 256] = (v1 - mu) * rstd * gam[threadIdx.x + 256] + bet[threadIdx.x + 256];
  op[threadIdx.x + 512] = (v2 - mu) * rstd * gam[threadIdx.x + 512] + bet[threadIdx.x + 512];
}

// ---------------- launch ----------------
extern "C" void kernel_launch(void* const* d_in, const int* in_sizes, int n_in,
                              void* d_out, int out_size, void* d_ws, size_t ws_size,
                              hipStream_t stream) {
  const float* hidden = (const float*)d_in[0];
  const float* Wq = (const float*)d_in[3];  const float* bq = (const float*)d_in[4];
  const float* Wk = (const float*)d_in[5];  const float* bk = (const float*)d_in[6];
  const float* Wv = (const float*)d_in[7];  const float* bv = (const float*)d_in[8];
  const float* Wqg = (const float*)d_in[9]; const float* bqg = (const float*)d_in[10];
  const float* Wkg = (const float*)d_in[11]; const float* bkg = (const float*)d_in[12];
  const float* Wvg = (const float*)d_in[13]; const float* bvg = (const float*)d_in[14];
  const float* Wo = (const float*)d_in[15]; const float* bo = (const float*)d_in[16];
  const float* gam = (const float*)d_in[17]; const float* bet = (const float*)d_in[18];

  char* ws = (char*)d_ws;
  const size_t SZH = (size_t)BB * HH * SS * HDD;  // 6,291,456 elems per proj
  unsigned short* xb = (unsigned short*)(ws);                                   // 12.58 MB; later: ctx
  unsigned short* Wt5 = (unsigned short*)(ws + 12582912);                       // 5.90 MB
  unsigned short* Wtqg = (unsigned short*)(ws + 12582912 + 5898240);            // 1.18 MB
  unsigned short* Wto = (unsigned short*)(ws + 12582912 + 5898240 + 1179648);   // 1.18 MB
  unsigned short* qkv = (unsigned short*)(ws + 20840448);                       // 5 x 12.58 MB
  unsigned short* qg = (unsigned short*)(ws + 20840448 + 62914560);             // 0.39 MB
  float* Opart = (float*)(ws + 84148224);                                       // 12.58 MB
  float* mlp = (float*)(ws + 84148224 + 12582912);                              // 0.39 MB
  unsigned short* ctx = xb;      // alias: xb dead after qg GEMM
  float* Y = (float*)qkv;        // alias: q/k slots dead after attention

  k_cvt<<<dim3((BB * SS * DD / 4 + 255) / 256), dim3(256), 0, stream>>>(hidden, xb, BB * SS * DD / 4);

  WArgs wa;
  wa.s[0] = Wq; wa.s[1] = Wk; wa.s[2] = Wv; wa.s[3] = Wkg; wa.s[4] = Wvg; wa.s[5] = Wqg; wa.s[6] = Wo;
  wa.d[0] = Wt5; wa.d[1] = Wt5 + 589824; wa.d[2] = Wt5 + 2 * 589824;
  wa.d[3] = Wt5 + 3 * 589824; wa.d[4] = Wt5 + 4 * 589824;
  wa.d[5] = Wtqg; wa.d[6] = Wto;
  k_tw<<<dim3(12, 12, 7), dim3(256), 0, stream>>>(wa);

  k_gemm<0><<<dim3(64, 30), dim3(256), 0, stream>>>(xb, Wt5, bq, bk, bv, bkg, bvg, qkv, nullptr, nullptr);
  k_gemm<1><<<dim3(2, 6), dim3(256), 0, stream>>>(xb, Wtqg, bqg, nullptr, nullptr, nullptr, nullptr, qg, nullptr, nullptr);

  // global-query attention: split-K partials, then band attention, then reduce
  k_attn<1><<<dim3(BB * HH * NSPLIT), dim3(512), 0, stream>>>(qg, qkv + 3 * SZH, qkv + 4 * SZH,
                                                              nullptr, Opart, mlp);
  k_attn<0><<<dim3(BB * HH * NBB), dim3(512), 0, stream>>>(qkv, qkv + SZH, qkv + 2 * SZH,
                                                           ctx, nullptr, nullptr);
  k_red<<<dim3(BB * HH * GG / 4), dim3(256), 0, stream>>>(Opart, mlp, ctx);

  k_gemm<2><<<dim3(64, 6), dim3(256), 0, stream>>>(ctx, Wto, bo, nullptr, nullptr, nullptr, nullptr, nullptr, Y, hidden);

  k_ln<<<dim3(BB * SS), dim3(256), 0, stream>>>(Y, gam, bet, (float*)d_out);
}

// Round 3
// 322.783 us; speedup vs baseline: 1.4729x; 1.1541x over previous
//
#include <hip/hip_runtime.h>
#include <stdint.h>

#define BB 2
#define SS 4096
#define DD 768
#define HH 12
#define HDD 64
#define WW 256
#define GG 128
#define NBB 16
#define NSPLIT 16

typedef __attribute__((ext_vector_type(4))) float f32x4;
typedef __attribute__((ext_vector_type(16))) float f32x16;
typedef __attribute__((ext_vector_type(8))) short bf16x8;
typedef __attribute__((ext_vector_type(4))) short s16x4;
typedef __attribute__((ext_vector_type(4))) unsigned short u16x4;

__device__ __forceinline__ unsigned short f2bf(float x) {
  union { float f; unsigned int u; } v; v.f = x;
  return (unsigned short)((v.u + 0x7fffu + ((v.u >> 16) & 1u)) >> 16);
}

__device__ __forceinline__ void async16(void* lds, const void* g) {
  __builtin_amdgcn_global_load_lds(
      (const __attribute__((address_space(1))) unsigned int*)g,
      (__attribute__((address_space(3))) unsigned int*)lds, 16, 0, 0);
}

__device__ __forceinline__ uint32_t lds_b(const void* p) {
  return (uint32_t)(uintptr_t)(__attribute__((address_space(3))) const void*)p;
}

__device__ __forceinline__ s16x4 tr_read(uint32_t addr) {
  s16x4 d;
  asm volatile("ds_read_b64_tr_b16 %0, %1" : "=v"(d) : "v"(addr) : "memory");
  return d;
}

__device__ __forceinline__ unsigned int cvtpk(float lo, float hi) {
  unsigned int d;
  asm("v_cvt_pk_bf16_f32 %0, %1, %2" : "=v"(d) : "v"(lo), "v"(hi));
  return d;
}

__device__ __forceinline__ void plswap(int& a, int& b) {
  auto r = __builtin_amdgcn_permlane32_swap(a, b, false, false);
  a = r[0]; b = r[1];
}

// value of x from the other 32-lane half (lane ^ 32)
__device__ __forceinline__ float xhalf(float x, int hi) {
  int a = __float_as_int(x), b = a;
  auto r = __builtin_amdgcn_permlane32_swap(a, b, false, false);
  return __int_as_float(hi ? r[0] : r[1]);
}

// ---------------- fp32 -> bf16 convert (x) ----------------
__global__ __launch_bounds__(256) void k_cvt(const float* __restrict__ x,
                                             unsigned short* __restrict__ o, int n4) {
  int i = blockIdx.x * 256 + threadIdx.x;
  if (i >= n4) return;
  f32x4 v = ((const f32x4*)x)[i];
  u16x4 r;
  r[0] = f2bf(v[0]); r[1] = f2bf(v[1]); r[2] = f2bf(v[2]); r[3] = f2bf(v[3]);
  ((u16x4*)o)[i] = r;
}

// ---------------- weight transpose + convert: Wt[n][k] = bf16(W[k][n]) ----------------
struct WArgs {
  const float* s[7];
  unsigned short* d[7];
};
__global__ __launch_bounds__(256) void k_tw(WArgs a) {
  __shared__ float t[64][65];
  const float* src = a.s[blockIdx.z];
  unsigned short* dst = a.d[blockIdx.z];
  int n0 = blockIdx.x * 64, k0 = blockIdx.y * 64;
#pragma unroll
  for (int it = 0; it < 16; ++it) {
    int idx = it * 256 + threadIdx.x;
    int r = idx >> 6, c = idx & 63;
    t[r][c] = src[(size_t)(k0 + r) * DD + n0 + c];
  }
  __syncthreads();
#pragma unroll
  for (int it = 0; it < 16; ++it) {
    int idx = it * 256 + threadIdx.x;
    int r = idx >> 6, c = idx & 63;
    dst[(size_t)(n0 + r) * DD + k0 + c] = f2bf(t[c][r]);
  }
}

// ---------------- GEMM: C = A(bf16, MxK) @ Wt^T(bf16, NxK) + bias ----------------
template <int OMODE>
__global__ __launch_bounds__(256) void k_gemm(
    const unsigned short* __restrict__ A, const unsigned short* __restrict__ Wt,
    const float* __restrict__ b0, const float* __restrict__ b1,
    const float* __restrict__ b2, const float* __restrict__ b3,
    const float* __restrict__ b4, unsigned short* __restrict__ outH,
    float* __restrict__ outY, const float* __restrict__ resid) {
  const int bm = blockIdx.x;
  int bn, p;
  if (OMODE == 0) { p = blockIdx.y / 6; bn = blockIdx.y % 6; }
  else { p = 0; bn = blockIdx.y; }
  const float* bias = b0;
  if (OMODE == 0) bias = (p == 0) ? b0 : (p == 1) ? b1 : (p == 2) ? b2 : (p == 3) ? b3 : b4;
  const float scale = (OMODE == 1 || (OMODE == 0 && p == 0)) ? 0.125f : 1.0f;

  __shared__ unsigned short Asm_[128 * 64];
  __shared__ unsigned short Bsm_[128 * 64];
  const int tid = threadIdx.x;
  const int l = tid & 63, w = tid >> 6;
  const int wr = w >> 1, wc = w & 1;
  const int g = l >> 4, ln = l & 15;
  const int l3 = l >> 3, l7 = l & 7;
  const int slotsrc = l7 ^ l3;

  f32x4 zf = {0.f, 0.f, 0.f, 0.f};
  f32x4 acc[4][4];
#pragma unroll
  for (int i = 0; i < 4; ++i)
#pragma unroll
    for (int j = 0; j < 4; ++j) acc[i][j] = zf;

  const int wtrow0 = (OMODE == 0 ? p * DD : 0) + bn * 128;

  for (int kt = 0; kt < 12; ++kt) {
#pragma unroll
    for (int i = 0; i < 4; ++i) {
      int u = i * 4 + w;
      int row = u * 8 + l3;
      int ar = bm * 128 + row;
      if (OMODE == 1) ar = ((ar >> 7) << 12) + (ar & 127);
      async16(&Asm_[u * 512], A + (size_t)ar * DD + kt * 64 + slotsrc * 8);
      async16(&Bsm_[u * 512], Wt + (size_t)(wtrow0 + row) * DD + kt * 64 + slotsrc * 8);
    }
    __syncthreads();
#pragma unroll
    for (int kc = 0; kc < 2; ++kc) {
      bf16x8 af[4], bfr[4];
#pragma unroll
      for (int t = 0; t < 4; ++t) {
        int arow = wr * 64 + t * 16 + ln;
        af[t] = *(const bf16x8*)&Asm_[arow * 64 + (((kc * 4 + g) ^ (arow & 7)) << 3)];
        int brow = wc * 64 + t * 16 + ln;
        bfr[t] = *(const bf16x8*)&Bsm_[brow * 64 + (((kc * 4 + g) ^ (brow & 7)) << 3)];
      }
#pragma unroll
      for (int ti = 0; ti < 4; ++ti)
#pragma unroll
        for (int tj = 0; tj < 4; ++tj)
          acc[ti][tj] = __builtin_amdgcn_mfma_f32_16x16x32_bf16(af[ti], bfr[tj], acc[ti][tj], 0, 0, 0);
    }
    __syncthreads();
  }

#pragma unroll
  for (int tj = 0; tj < 4; ++tj) {
    int nl = bn * 128 + wc * 64 + tj * 16 + ln;  // 0..767
    float bv = bias[nl];
#pragma unroll
    for (int ti = 0; ti < 4; ++ti) {
#pragma unroll
      for (int r = 0; r < 4; ++r) {
        int m = bm * 128 + wr * 64 + ti * 16 + g * 4 + r;
        float val = acc[ti][tj][r] + bv;
        if (OMODE == 2) {
          outY[(size_t)m * DD + nl] = val + resid[(size_t)m * DD + nl];
        } else if (OMODE == 0) {
          val *= scale;
          int b = m >> 12, s = m & 4095, h = nl >> 6, d = nl & 63;
          outH[(size_t)p * (BB * HH * SS * HDD) +
               (((size_t)(b * HH + h) * SS + s) * HDD) + d] = f2bf(val);
        } else {
          val *= scale;
          int b = m >> 7, gi = m & 127, h = nl >> 6, d = nl & 63;
          outH[(((size_t)(b * HH + h) * GG + gi) * HDD) + d] = f2bf(val);
        }
      }
    }
  }
}

// ---------------- attention (32x32 swapped-QK^T, in-register softmax) ----------------
// MODE 0: banded + global-keys. 512 thr, 8 waves x 32 q = 256 q/block. out -> ctx
// MODE 1: global-query full attn, split-K. 256 thr, 4 waves x 32 q = 128 q/block.
//         unnormalized partial O + (m2,l) -> workspace
template <int MODE>
__global__ __launch_bounds__((MODE == 0) ? 512 : 256, 4) void k_attn(
    const unsigned short* __restrict__ qbuf, const unsigned short* __restrict__ kbuf,
    const unsigned short* __restrict__ vbuf, unsigned short* __restrict__ ctx,
    float* __restrict__ Opart, float* __restrict__ mlp) {
  constexpr int NW = (MODE == 0) ? 8 : 4;
  constexpr int NSTG = (MODE == 0) ? 1 : 2;
  constexpr float L2E = 1.4426950408889634f;

  __shared__ unsigned short Ksm[2][64 * 64];
  __shared__ unsigned short Vsm[2][64 * 64];  // subtiled [key/4][d/16][4][16]
  __shared__ __align__(16) float Alds[NW][32];

  const int tid = threadIdx.x;
  const int l = tid & 63, w = tid >> 6;
  const int l31 = l & 31, hi = l >> 5;
  const int l3 = l >> 3, l7 = l & 7;

  int b, h, n, split;
  if (MODE == 0) {
    n = blockIdx.x & 15; h = (blockIdx.x >> 4) % 12; b = blockIdx.x / (16 * 12); split = 0;
  } else {
    split = blockIdx.x & 15; int bhid = blockIdx.x >> 4; h = bhid % 12; b = bhid / 12; n = 0;
  }

  const size_t bh = (size_t)(b * HH + h);
  const unsigned short* qp = qbuf + bh * (size_t)((MODE == 0) ? SS * HDD : GG * HDD);
  const unsigned short* kp = kbuf + bh * (size_t)(SS * HDD);
  const unsigned short* vp = vbuf + bh * (size_t)(SS * HDD);

  // chunk geometry (arithmetic, no arrays)
  int bstart = 0, nch;
  if (MODE == 0) {
    bstart = n * 256 - 256;
    int s0 = bstart < GG ? GG : bstart;
    int e0 = bstart + 768; if (e0 > SS) e0 = SS;
    nch = 2 + ((e0 - s0) >> 6);
    bstart = s0;
  } else {
    nch = 4;
  }
  const int qrow0 = (MODE == 0) ? (n * 256 + w * 32) : (w * 32);

  // Q fragments (B-operand): lane holds Q[qrow0 + l31][kd*16 + hi*8 + j]
  bf16x8 qf[4];
#pragma unroll
  for (int kd = 0; kd < 4; ++kd)
    qf[kd] = *(const bf16x8*)&qp[(size_t)(qrow0 + l31) * HDD + kd * 16 + hi * 8];

  f32x16 O[2];
#pragma unroll
  for (int dt = 0; dt < 2; ++dt)
#pragma unroll
    for (int r = 0; r < 16; ++r) O[dt][r] = 0.f;
  float m2 = -1e30f, lsum = 0.f;

  const uint32_t vbase = lds_b(Vsm);
  int vwoff[NSTG];
  {
    int key0 = tid >> 3, dc = tid & 7;
#pragma unroll
    for (int u = 0; u < NSTG; ++u) {
      int key = u * 32 + key0;
      vwoff[u] = (((key >> 2) << 8) | ((dc >> 1) << 6) | ((key & 3) << 4) | ((dc & 1) << 3));
    }
  }

#define KB_OF(ci) ((ci) < 2 && MODE == 0 ? (ci) * 64 : (MODE == 0 ? bstart + ((ci) - 2) * 64 : ((split * 4 + (ci)) * 64)))

  // prologue: stage chunk 0 into buf 0
  bf16x8 vv[NSTG];
  {
    int kb = KB_OF(0);
#pragma unroll
    for (int u = 0; u < NSTG; ++u) {
      async16(&Ksm[0][(u * NW + w) * 512],
              kp + (size_t)(kb + (u * NW + w) * 8 + l3) * HDD + ((l7 ^ l3) << 3));
      vv[u] = *(const bf16x8*)&vp[(size_t)(kb + u * 32 + (tid >> 3)) * HDD + ((tid & 7) << 3)];
    }
  }
  int buf = 0;

  for (int ci = 0; ci < nch; ++ci) {
    const int kbase = KB_OF(ci);
    asm volatile("s_waitcnt vmcnt(0)" ::: "memory");  // K(ci) in LDS, V(ci) in regs
#pragma unroll
    for (int u = 0; u < NSTG; ++u) *(bf16x8*)&Vsm[buf][vwoff[u]] = vv[u];
    __syncthreads();

    if (ci + 1 < nch) {  // prefetch next chunk (hides under compute)
      int kb = KB_OF(ci + 1);
#pragma unroll
      for (int u = 0; u < NSTG; ++u) {
        async16(&Ksm[buf ^ 1][(u * NW + w) * 512],
                kp + (size_t)(kb + (u * NW + w) * 8 + l3) * HDD + ((l7 ^ l3) << 3));
        vv[u] = *(const bf16x8*)&vp[(size_t)(kb + u * 32 + (tid >> 3)) * HDD + ((tid & 7) << 3)];
      }
    }

    // ---- QK^T: sc[s] = K_sub(s) . Q^T, P[key][q], q = l31 per lane ----
    f32x16 sc[2];
#pragma unroll
    for (int s = 0; s < 2; ++s)
#pragma unroll
      for (int r = 0; r < 16; ++r) sc[s][r] = 0.f;
    __builtin_amdgcn_s_setprio(1);
#pragma unroll
    for (int kd = 0; kd < 4; ++kd) {
#pragma unroll
      for (int s = 0; s < 2; ++s) {
        int row = s * 32 + l31;
        bf16x8 kf = *(const bf16x8*)&Ksm[buf][row * 64 + ((((kd << 1) + hi) ^ (row & 7)) << 3)];
        sc[s] = __builtin_amdgcn_mfma_f32_32x32x16_bf16(kf, qf[kd], sc[s], 0, 0, 0);
      }
    }
    __builtin_amdgcn_s_setprio(0);

    // ---- band mask ----
    if (MODE == 0 && kbase >= GG) {
      const int base0 = (kbase - (n * 256 - 256)) - (w * 32 + l31);
#pragma unroll
      for (int s = 0; s < 2; ++s)
#pragma unroll
        for (int r = 0; r < 16; ++r) {
          int t = base0 + s * 32 + (r & 3) + 8 * (r >> 2) + 4 * hi;
          if ((unsigned)t > 512u) sc[s][r] = -1e9f;
        }
    }

    // ---- online softmax (per-lane q row; exp2 domain) ----
    float mh = sc[0][0];
#pragma unroll
    for (int s = 0; s < 2; ++s)
#pragma unroll
      for (int r = 0; r < 16; ++r) if (s || r) mh = fmaxf(mh, sc[s][r]);
    mh = fmaxf(mh, xhalf(mh, hi));
    float mnew = fmaxf(m2, mh * L2E);
    float alpha = exp2f(m2 - mnew);
    m2 = mnew;
    float sh = 0.f;
#pragma unroll
    for (int s = 0; s < 2; ++s)
#pragma unroll
      for (int r = 0; r < 16; ++r) {
        float pv = exp2f(__builtin_fmaf(sc[s][r], L2E, -mnew));
        sc[s][r] = pv;
        sh += pv;
      }
    sh += xhalf(sh, hi);
    lsum = lsum * alpha + sh;

    // ---- O rescale: alpha[q] broadcast (q per reg) ----
    if (l < 32) Alds[w][l] = alpha;
    f32x4 aT[4];
#pragma unroll
    for (int g2 = 0; g2 < 4; ++g2) aT[g2] = *(const f32x4*)&Alds[w][g2 * 8 + hi * 4];
#pragma unroll
    for (int dt = 0; dt < 2; ++dt)
#pragma unroll
      for (int r = 0; r < 16; ++r) O[dt][r] *= aT[r >> 2][r & 3];

    // ---- pack P -> A-fragments (cvt_pk + permlane32_swap, in-register) ----
    bf16x8 pa[4];
#pragma unroll
    for (int kk = 0; kk < 4; ++kk) {
      const int s = kk >> 1, h8 = (kk & 1) * 8;
      int x0 = (int)cvtpk(sc[s][h8 + 0], sc[s][h8 + 1]);
      int x1 = (int)cvtpk(sc[s][h8 + 2], sc[s][h8 + 3]);
      int y0 = (int)cvtpk(sc[s][h8 + 4], sc[s][h8 + 5]);
      int y1 = (int)cvtpk(sc[s][h8 + 6], sc[s][h8 + 7]);
      plswap(x0, y0); plswap(x1, y1);
      union { int u[4]; bf16x8 v; } pk;
      pk.u[0] = x0; pk.u[1] = x1; pk.u[2] = y0; pk.u[3] = y1;
      pa[kk] = pk.v;
    }

    // ---- PV: O[dt] += P . V ----
    const uint32_t vb = vbase + (uint32_t)(buf << 13);
#pragma unroll
    for (int dt = 0; dt < 2; ++dt) {
      s16x4 t0[4], t1[4];
#pragma unroll
      for (int kk = 0; kk < 4; ++kk) {
        int kg = kk * 4 + hi * 2;
        int dgrp = dt * 2 + (l31 >> 4);
        uint32_t a = vb + (uint32_t)((kg * 256 + dgrp * 64 + (l31 & 15)) << 1);
        t0[kk] = tr_read(a);
        t1[kk] = tr_read(a + 512);
      }
      asm volatile("s_waitcnt lgkmcnt(0)" ::: "memory");
      __builtin_amdgcn_sched_barrier(0);
      __builtin_amdgcn_s_setprio(1);
#pragma unroll
      for (int kk = 0; kk < 4; ++kk) {
        bf16x8 vf = __builtin_shufflevector(t0[kk], t1[kk], 0, 1, 2, 3, 4, 5, 6, 7);
        O[dt] = __builtin_amdgcn_mfma_f32_32x32x16_bf16(pa[kk], vf, O[dt], 0, 0, 0);
      }
      __builtin_amdgcn_s_setprio(0);
    }

    buf ^= 1;
  }

  // ---- epilogue ----
  if (MODE == 0) {
    if (l < 32) Alds[w][l] = 1.f / lsum;
    f32x4 iT[4];
#pragma unroll
    for (int g2 = 0; g2 < 4; ++g2) iT[g2] = *(const f32x4*)&Alds[w][g2 * 8 + hi * 4];
#pragma unroll
    for (int dt = 0; dt < 2; ++dt)
#pragma unroll
      for (int r = 0; r < 16; ++r) {
        int q = qrow0 + (r & 3) + 8 * (r >> 2) + 4 * hi;
        int d = dt * 32 + l31;
        ctx[((size_t)b * SS + q) * DD + h * HDD + d] = f2bf(O[dt][r] * iT[r >> 2][r & 3]);
      }
  } else {
    size_t pb = (bh * NSPLIT + split) * (size_t)GG;
#pragma unroll
    for (int dt = 0; dt < 2; ++dt)
#pragma unroll
      for (int r = 0; r < 16; ++r) {
        int q = w * 32 + (r & 3) + 8 * (r >> 2) + 4 * hi;
        Opart[(pb + q) * HDD + dt * 32 + l31] = O[dt][r];
      }
    if (l < 32) {
      size_t mb = (pb + w * 32 + l) * 2;
      mlp[mb] = m2;
      mlp[mb + 1] = lsum;
    }
  }
#undef KB_OF
}

// ---------------- split-K reduce for global queries (m in exp2 domain) ----------------
__global__ __launch_bounds__(256) void k_red(const float* __restrict__ Opart,
                                             const float* __restrict__ mlp,
                                             unsigned short* __restrict__ ctx) {
  int wid = blockIdx.x * 4 + (threadIdx.x >> 6);  // 0..3071 = bh*128 + q
  int d = threadIdx.x & 63;
  int bh = wid >> 7, q = wid & 127;
  int b = bh / HH, h = bh % HH;

  float mmax = -1e30f;
#pragma unroll
  for (int s = 0; s < NSPLIT; ++s)
    mmax = fmaxf(mmax, mlp[(((size_t)bh * NSPLIT + s) * GG + q) * 2]);
  float acc = 0.f, denom = 0.f;
#pragma unroll
  for (int s = 0; s < NSPLIT; ++s) {
    size_t mb = (((size_t)bh * NSPLIT + s) * GG + q) * 2;
    float wgt = exp2f(mlp[mb] - mmax);
    denom += wgt * mlp[mb + 1];
    acc += wgt * Opart[(((size_t)bh * NSPLIT + s) * GG + q) * HDD + d];
  }
  ctx[((size_t)b * SS + q) * DD + h * HDD + d] = f2bf(acc / denom);
}

// ---------------- layernorm ----------------
__global__ __launch_bounds__(256) void k_ln(const float* __restrict__ Y,
                                            const float* __restrict__ gam,
                                            const float* __restrict__ bet,
                                            float* __restrict__ outp) {
  const int row = blockIdx.x;
  const float* y = Y + (size_t)row * DD;
  float v0 = y[threadIdx.x], v1 = y[threadIdx.x + 256], v2 = y[threadIdx.x + 512];
  float s = v0 + v1 + v2, s2 = v0 * v0 + v1 * v1 + v2 * v2;
#pragma unroll
  for (int d = 1; d < 64; d <<= 1) { s += __shfl_xor(s, d, 64); s2 += __shfl_xor(s2, d, 64); }
  __shared__ float r1[4], r2[4];
  int w = threadIdx.x >> 6, l = threadIdx.x & 63;
  if (l == 0) { r1[w] = s; r2[w] = s2; }
  __syncthreads();
  s = r1[0] + r1[1] + r1[2] + r1[3];
  s2 = r2[0] + r2[1] + r2[2] + r2[3];
  float mu = s * (1.f / 768.f);
  float var = s2 * (1.f / 768.f) - mu * mu;
  float rstd = rsqrtf(var + 1e-5f);
  float* op = outp + (size_t)row * DD;
  op[threadIdx.x] = (v0 - mu) * rstd * gam[threadIdx.x] + bet[threadIdx.x];
  op[threadIdx.x + 256] = (v1 - mu) * rstd * gam[threadIdx.x + 256] + bet[threadIdx.x + 256];
  op[threadIdx.x + 512] = (v2 - mu) * rstd * gam[threadIdx.x + 512] + bet[threadIdx.x + 512];
}

// ---------------- launch ----------------
extern "C" void kernel_launch(void* const* d_in, const int* in_sizes, int n_in,
                              void* d_out, int out_size, void* d_ws, size_t ws_size,
                              hipStream_t stream) {
  const float* hidden = (const float*)d_in[0];
  const float* Wq = (const float*)d_in[3];  const float* bq = (const float*)d_in[4];
  const float* Wk = (const float*)d_in[5];  const float* bk = (const float*)d_in[6];
  const float* Wv = (const float*)d_in[7];  const float* bv = (const float*)d_in[8];
  const float* Wqg = (const float*)d_in[9]; const float* bqg = (const float*)d_in[10];
  const float* Wkg = (const float*)d_in[11]; const float* bkg = (const float*)d_in[12];
  const float* Wvg = (const float*)d_in[13]; const float* bvg = (const float*)d_in[14];
  const float* Wo = (const float*)d_in[15]; const float* bo = (const float*)d_in[16];
  const float* gam = (const float*)d_in[17]; const float* bet = (const float*)d_in[18];

  char* ws = (char*)d_ws;
  const size_t SZH = (size_t)BB * HH * SS * HDD;  // 6,291,456 elems per proj
  unsigned short* xb = (unsigned short*)(ws);                                   // 12.58 MB; later: ctx
  unsigned short* Wt5 = (unsigned short*)(ws + 12582912);                       // 5.90 MB
  unsigned short* Wtqg = (unsigned short*)(ws + 12582912 + 5898240);            // 1.18 MB
  unsigned short* Wto = (unsigned short*)(ws + 12582912 + 5898240 + 1179648);   // 1.18 MB
  unsigned short* qkv = (unsigned short*)(ws + 20840448);                       // 5 x 12.58 MB
  unsigned short* qg = (unsigned short*)(ws + 20840448 + 62914560);             // 0.39 MB
  float* Opart = (float*)(ws + 84148224);                                       // 12.58 MB
  float* mlp = (float*)(ws + 84148224 + 12582912);                              // 0.39 MB
  unsigned short* ctx = xb;      // alias: xb dead after qg GEMM
  float* Y = (float*)qkv;        // alias: q/k slots dead after attention

  k_cvt<<<dim3((BB * SS * DD / 4 + 255) / 256), dim3(256), 0, stream>>>(hidden, xb, BB * SS * DD / 4);

  WArgs wa;
  wa.s[0] = Wq; wa.s[1] = Wk; wa.s[2] = Wv; wa.s[3] = Wkg; wa.s[4] = Wvg; wa.s[5] = Wqg; wa.s[6] = Wo;
  wa.d[0] = Wt5; wa.d[1] = Wt5 + 589824; wa.d[2] = Wt5 + 2 * 589824;
  wa.d[3] = Wt5 + 3 * 589824; wa.d[4] = Wt5 + 4 * 589824;
  wa.d[5] = Wtqg; wa.d[6] = Wto;
  k_tw<<<dim3(12, 12, 7), dim3(256), 0, stream>>>(wa);

  k_gemm<0><<<dim3(64, 30), dim3(256), 0, stream>>>(xb, Wt5, bq, bk, bv, bkg, bvg, qkv, nullptr, nullptr);
  k_gemm<1><<<dim3(2, 6), dim3(256), 0, stream>>>(xb, Wtqg, bqg, nullptr, nullptr, nullptr, nullptr, qg, nullptr, nullptr);

  // global-query attention: split-K partials, then band attention, then reduce
  k_attn<1><<<dim3(BB * HH * NSPLIT), dim3(256), 0, stream>>>(qg, qkv + 3 * SZH, qkv + 4 * SZH,
                                                              nullptr, Opart, mlp);
  k_attn<0><<<dim3(BB * HH * NBB), dim3(512), 0, stream>>>(qkv, qkv + SZH, qkv + 2 * SZH,
                                                           ctx, nullptr, nullptr);
  k_red<<<dim3(BB * HH * GG / 4), dim3(256), 0, stream>>>(Opart, mlp, ctx);

  k_gemm<2><<<dim3(64, 6), dim3(256), 0, stream>>>(ctx, Wto, bo, nullptr, nullptr, nullptr, nullptr, nullptr, Y, hidden);

  k_ln<<<dim3(BB * SS), dim3(256), 0, stream>>>(Y, gam, bet, (float*)d_out);
}

// Round 4
// 321.513 us; speedup vs baseline: 1.4787x; 1.0040x over previous
//
#include <hip/hip_runtime.h>
#include <stdint.h>

#define BB 2
#define SS 4096
#define DD 768
#define HH 12
#define HDD 64
#define WW 256
#define GG 128
#define NBB 16
#define NSPLIT 16

typedef __attribute__((ext_vector_type(4))) float f32x4;
typedef __attribute__((ext_vector_type(16))) float f32x16;
typedef __attribute__((ext_vector_type(8))) short bf16x8;
typedef __attribute__((ext_vector_type(4))) short s16x4;
typedef __attribute__((ext_vector_type(4))) unsigned short u16x4;

__device__ __forceinline__ unsigned short f2bf(float x) {
  union { float f; unsigned int u; } v; v.f = x;
  return (unsigned short)((v.u + 0x7fffu + ((v.u >> 16) & 1u)) >> 16);
}

__device__ __forceinline__ void async16(void* lds, const void* g) {
  __builtin_amdgcn_global_load_lds(
      (const __attribute__((address_space(1))) unsigned int*)g,
      (__attribute__((address_space(3))) unsigned int*)lds, 16, 0, 0);
}

__device__ __forceinline__ uint32_t lds_b(const void* p) {
  return (uint32_t)(uintptr_t)(__attribute__((address_space(3))) const void*)p;
}

__device__ __forceinline__ s16x4 tr_read(uint32_t addr) {
  s16x4 d;
  asm volatile("ds_read_b64_tr_b16 %0, %1" : "=v"(d) : "v"(addr) : "memory");
  return d;
}

__device__ __forceinline__ unsigned int cvtpk(float lo, float hi) {
  unsigned int d;
  asm("v_cvt_pk_bf16_f32 %0, %1, %2" : "=v"(d) : "v"(lo), "v"(hi));
  return d;
}

__device__ __forceinline__ void plswap(int& a, int& b) {
  auto r = __builtin_amdgcn_permlane32_swap(a, b, false, false);
  a = r[0]; b = r[1];
}

// value of x from the other 32-lane half (lane ^ 32)
__device__ __forceinline__ float xhalf(float x, int hi) {
  int a = __float_as_int(x), b = a;
  auto r = __builtin_amdgcn_permlane32_swap(a, b, false, false);
  return __int_as_float(hi ? r[0] : r[1]);
}

// ---------------- fp32 -> bf16 convert (x) ----------------
__global__ __launch_bounds__(256) void k_cvt(const float* __restrict__ x,
                                             unsigned short* __restrict__ o, int n4) {
  int i = blockIdx.x * 256 + threadIdx.x;
  if (i >= n4) return;
  f32x4 v = ((const f32x4*)x)[i];
  u16x4 r;
  r[0] = f2bf(v[0]); r[1] = f2bf(v[1]); r[2] = f2bf(v[2]); r[3] = f2bf(v[3]);
  ((u16x4*)o)[i] = r;
}

// ---------------- weight transpose + convert: Wt[n][k] = bf16(W[k][n]) ----------------
struct WArgs {
  const float* s[7];
  unsigned short* d[7];
};
__global__ __launch_bounds__(256) void k_tw(WArgs a) {
  __shared__ float t[64][65];
  const float* src = a.s[blockIdx.z];
  unsigned short* dst = a.d[blockIdx.z];
  int n0 = blockIdx.x * 64, k0 = blockIdx.y * 64;
#pragma unroll
  for (int it = 0; it < 16; ++it) {
    int idx = it * 256 + threadIdx.x;
    int r = idx >> 6, c = idx & 63;
    t[r][c] = src[(size_t)(k0 + r) * DD + n0 + c];
  }
  __syncthreads();
#pragma unroll
  for (int it = 0; it < 16; ++it) {
    int idx = it * 256 + threadIdx.x;
    int r = idx >> 6, c = idx & 63;
    dst[(size_t)(n0 + r) * DD + k0 + c] = f2bf(t[c][r]);
  }
}

// ---------------- 256x256 deep-pipelined GEMM (counted vmcnt, dbuf LDS) ----------
// OMODE 0: fused 5-projection, heads layout out. flat grid 480 (XCD-swizzled).
__device__ __forceinline__ void stage_tile(unsigned short* Abuf, unsigned short* Bbuf,
                                           const unsigned short* ag,
                                           const unsigned short* bg, int tid) {
#pragma unroll
  for (int u = 0; u < 4; ++u) {
    async16(&Abuf[u * 4096 + tid * 8], ag + (size_t)u * 64 * DD);
    async16(&Bbuf[u * 4096 + tid * 8], bg + (size_t)u * 64 * DD);
  }
}

template <int OMODE>
__global__ __launch_bounds__(512, 2) void k_gemm256(
    const unsigned short* __restrict__ A, const unsigned short* __restrict__ Wt,
    const float* __restrict__ b0, const float* __restrict__ b1,
    const float* __restrict__ b2, const float* __restrict__ b3,
    const float* __restrict__ b4, unsigned short* __restrict__ outH,
    float* __restrict__ outY, const float* __restrict__ resid) {
  constexpr int NCOL = (OMODE == 0) ? 15 : 3;
  const int nwg = 32 * NCOL;
  // bijective XCD swizzle (nwg % 8 == 0)
  const int sw = (blockIdx.x & 7) * (nwg >> 3) + (blockIdx.x >> 3);
  const int bx = sw & 31, by = sw >> 5;
  const int M0 = bx * 256, N0 = by * 256;
  const int p = (OMODE == 0) ? (by / 3) : 0;
  const int N0p = N0 - p * DD;
  const float* bias = b0;
  if (OMODE == 0) bias = (p == 0) ? b0 : (p == 1) ? b1 : (p == 2) ? b2 : (p == 3) ? b3 : b4;
  const float scale = (OMODE == 0 && p == 0) ? 0.125f : 1.0f;
  const int WT0 = p * DD + N0p;

  __shared__ unsigned short Al[2][256 * 64];
  __shared__ unsigned short Bl[2][256 * 64];

  const int tid = threadIdx.x;
  const int l = tid & 63, w = tid >> 6;
  const int wr = w >> 2, wc = w & 3;        // 2 x 4 wave grid; per-wave 128 x 64
  const int g = l >> 4, ln = l & 15;
  const int trow = tid >> 3;
  const int tslot = (tid & 7) ^ (trow & 7);

  f32x4 acc[8][4];
#pragma unroll
  for (int i = 0; i < 8; ++i)
#pragma unroll
    for (int j = 0; j < 4; ++j) acc[i][j] = (f32x4){0.f, 0.f, 0.f, 0.f};

  const unsigned short* ag0 = A + (size_t)(M0 + trow) * DD + tslot * 8;
  const unsigned short* bg0 = Wt + (size_t)(WT0 + trow) * DD + tslot * 8;

  // prologue: stage tiles 0 and 1 (16 loads in flight)
  stage_tile(Al[0], Bl[0], ag0, bg0, tid);
  stage_tile(Al[1], Bl[1], ag0 + 64, bg0 + 64, tid);

  for (int kt = 0; kt < 12; ++kt) {
    const int bb = kt & 1;
    // own share of tile kt landed (tile kt+1's 8 loads stay in flight)
    asm volatile("s_waitcnt vmcnt(8)" ::: "memory");
    __builtin_amdgcn_s_barrier();   // whole tile kt visible to all waves

    bf16x8 af[2][8], bfr[2][4];
#pragma unroll
    for (int kc = 0; kc < 2; ++kc) {
#pragma unroll
      for (int ti = 0; ti < 8; ++ti) {
        int row = wr * 128 + ti * 16 + ln;
        af[kc][ti] = *(const bf16x8*)&Al[bb][row * 64 + (((kc * 4 + g) ^ (row & 7)) << 3)];
      }
#pragma unroll
      for (int tj = 0; tj < 4; ++tj) {
        int row = wc * 64 + tj * 16 + ln;
        bfr[kc][tj] = *(const bf16x8*)&Bl[bb][row * 64 + (((kc * 4 + g) ^ (row & 7)) << 3)];
      }
    }
    __builtin_amdgcn_s_setprio(1);
#pragma unroll
    for (int kc = 0; kc < 2; ++kc)
#pragma unroll
      for (int ti = 0; ti < 8; ++ti)
#pragma unroll
        for (int tj = 0; tj < 4; ++tj)
          acc[ti][tj] = __builtin_amdgcn_mfma_f32_16x16x32_bf16(af[kc][ti], bfr[kc][tj],
                                                                acc[ti][tj], 0, 0, 0);
    __builtin_amdgcn_s_setprio(0);
    asm volatile("s_waitcnt lgkmcnt(0)" ::: "memory");
    __builtin_amdgcn_sched_barrier(0);
    __builtin_amdgcn_s_barrier();   // all waves done reading buf bb
    if (kt + 2 < 12)                // stage tile kt+2 into the buffer just freed
      stage_tile(Al[bb], Bl[bb], ag0 + (kt + 2) * 64, bg0 + (kt + 2) * 64, tid);
  }

  // ---- epilogue ----
#pragma unroll
  for (int tj = 0; tj < 4; ++tj) {
    int npp = N0p + wc * 64 + tj * 16 + ln;
    float bv = bias[npp];
#pragma unroll
    for (int ti = 0; ti < 8; ++ti) {
#pragma unroll
      for (int r2 = 0; r2 < 4; ++r2) {
        int m = M0 + wr * 128 + ti * 16 + g * 4 + r2;
        float val = acc[ti][tj][r2] + bv;
        if (OMODE == 2) {
          outY[(size_t)m * DD + npp] = val + resid[(size_t)m * DD + npp];
        } else {
          val *= scale;
          int b = m >> 12, s = m & 4095, h = npp >> 6, d = npp & 63;
          outH[(size_t)p * (BB * HH * SS * HDD) +
               (((size_t)(b * HH + h) * SS + s) * HDD) + d] = f2bf(val);
        }
      }
    }
  }
}

// ---------------- GEMM: C = A(bf16, MxK) @ Wt^T(bf16, NxK) + bias ----------------
// OMODE 1: qg (M=256, row-remapped input); OMODE 2: out-proj fp32 + resid
template <int OMODE>
__global__ __launch_bounds__(256) void k_gemm(
    const unsigned short* __restrict__ A, const unsigned short* __restrict__ Wt,
    const float* __restrict__ b0, const float* __restrict__ b1,
    const float* __restrict__ b2, const float* __restrict__ b3,
    const float* __restrict__ b4, unsigned short* __restrict__ outH,
    float* __restrict__ outY, const float* __restrict__ resid) {
  const int bm = blockIdx.x;
  int bn, p;
  if (OMODE == 0) { p = blockIdx.y / 6; bn = blockIdx.y % 6; }
  else { p = 0; bn = blockIdx.y; }
  const float* bias = b0;
  if (OMODE == 0) bias = (p == 0) ? b0 : (p == 1) ? b1 : (p == 2) ? b2 : (p == 3) ? b3 : b4;
  const float scale = (OMODE == 1 || (OMODE == 0 && p == 0)) ? 0.125f : 1.0f;

  __shared__ unsigned short Asm_[128 * 64];
  __shared__ unsigned short Bsm_[128 * 64];
  const int tid = threadIdx.x;
  const int l = tid & 63, w = tid >> 6;
  const int wr = w >> 1, wc = w & 1;
  const int g = l >> 4, ln = l & 15;
  const int l3 = l >> 3, l7 = l & 7;
  const int slotsrc = l7 ^ l3;

  f32x4 zf = {0.f, 0.f, 0.f, 0.f};
  f32x4 acc[4][4];
#pragma unroll
  for (int i = 0; i < 4; ++i)
#pragma unroll
    for (int j = 0; j < 4; ++j) acc[i][j] = zf;

  const int wtrow0 = (OMODE == 0 ? p * DD : 0) + bn * 128;

  for (int kt = 0; kt < 12; ++kt) {
#pragma unroll
    for (int i = 0; i < 4; ++i) {
      int u = i * 4 + w;
      int row = u * 8 + l3;
      int ar = bm * 128 + row;
      if (OMODE == 1) ar = ((ar >> 7) << 12) + (ar & 127);
      async16(&Asm_[u * 512], A + (size_t)ar * DD + kt * 64 + slotsrc * 8);
      async16(&Bsm_[u * 512], Wt + (size_t)(wtrow0 + row) * DD + kt * 64 + slotsrc * 8);
    }
    __syncthreads();
#pragma unroll
    for (int kc = 0; kc < 2; ++kc) {
      bf16x8 af[4], bfr[4];
#pragma unroll
      for (int t = 0; t < 4; ++t) {
        int arow = wr * 64 + t * 16 + ln;
        af[t] = *(const bf16x8*)&Asm_[arow * 64 + (((kc * 4 + g) ^ (arow & 7)) << 3)];
        int brow = wc * 64 + t * 16 + ln;
        bfr[t] = *(const bf16x8*)&Bsm_[brow * 64 + (((kc * 4 + g) ^ (brow & 7)) << 3)];
      }
#pragma unroll
      for (int ti = 0; ti < 4; ++ti)
#pragma unroll
        for (int tj = 0; tj < 4; ++tj)
          acc[ti][tj] = __builtin_amdgcn_mfma_f32_16x16x32_bf16(af[ti], bfr[tj], acc[ti][tj], 0, 0, 0);
    }
    __syncthreads();
  }

#pragma unroll
  for (int tj = 0; tj < 4; ++tj) {
    int nl = bn * 128 + wc * 64 + tj * 16 + ln;  // 0..767
    float bv = bias[nl];
#pragma unroll
    for (int ti = 0; ti < 4; ++ti) {
#pragma unroll
      for (int r = 0; r < 4; ++r) {
        int m = bm * 128 + wr * 64 + ti * 16 + g * 4 + r;
        float val = acc[ti][tj][r] + bv;
        if (OMODE == 2) {
          outY[(size_t)m * DD + nl] = val + resid[(size_t)m * DD + nl];
        } else if (OMODE == 0) {
          val *= scale;
          int b = m >> 12, s = m & 4095, h = nl >> 6, d = nl & 63;
          outH[(size_t)p * (BB * HH * SS * HDD) +
               (((size_t)(b * HH + h) * SS + s) * HDD) + d] = f2bf(val);
        } else {
          val *= scale;
          int b = m >> 7, gi = m & 127, h = nl >> 6, d = nl & 63;
          outH[(((size_t)(b * HH + h) * GG + gi) * HDD) + d] = f2bf(val);
        }
      }
    }
  }
}

// ---------------- attention (32x32 swapped-QK^T, in-register softmax) ----------------
// MODE 0: banded + global-keys. 512 thr, 8 waves x 32 q = 256 q/block. out -> ctx
// MODE 1: global-query full attn, split-K. 256 thr, 4 waves x 32 q = 128 q/block.
//         unnormalized partial O + (m2,l) -> workspace
template <int MODE>
__global__ __launch_bounds__((MODE == 0) ? 512 : 256, 4) void k_attn(
    const unsigned short* __restrict__ qbuf, const unsigned short* __restrict__ kbuf,
    const unsigned short* __restrict__ vbuf, unsigned short* __restrict__ ctx,
    float* __restrict__ Opart, float* __restrict__ mlp) {
  constexpr int NW = (MODE == 0) ? 8 : 4;
  constexpr int NSTG = (MODE == 0) ? 1 : 2;
  constexpr float L2E = 1.4426950408889634f;

  __shared__ unsigned short Ksm[2][64 * 64];
  __shared__ unsigned short Vsm[2][64 * 64];  // subtiled [key/4][d/16][4][16]
  __shared__ __align__(16) float Alds[NW][32];

  const int tid = threadIdx.x;
  const int l = tid & 63, w = tid >> 6;
  const int l31 = l & 31, hi = l >> 5;
  const int l3 = l >> 3, l7 = l & 7;

  int b, h, n, split;
  if (MODE == 0) {
    n = blockIdx.x & 15; h = (blockIdx.x >> 4) % 12; b = blockIdx.x / (16 * 12); split = 0;
  } else {
    split = blockIdx.x & 15; int bhid = blockIdx.x >> 4; h = bhid % 12; b = bhid / 12; n = 0;
  }

  const size_t bh = (size_t)(b * HH + h);
  const unsigned short* qp = qbuf + bh * (size_t)((MODE == 0) ? SS * HDD : GG * HDD);
  const unsigned short* kp = kbuf + bh * (size_t)(SS * HDD);
  const unsigned short* vp = vbuf + bh * (size_t)(SS * HDD);

  // chunk geometry (arithmetic, no arrays)
  int bstart = 0, nch;
  if (MODE == 0) {
    bstart = n * 256 - 256;
    int s0 = bstart < GG ? GG : bstart;
    int e0 = bstart + 768; if (e0 > SS) e0 = SS;
    nch = 2 + ((e0 - s0) >> 6);
    bstart = s0;
  } else {
    nch = 4;
  }
  const int qrow0 = (MODE == 0) ? (n * 256 + w * 32) : (w * 32);

  // Q fragments (B-operand): lane holds Q[qrow0 + l31][kd*16 + hi*8 + j]
  bf16x8 qf[4];
#pragma unroll
  for (int kd = 0; kd < 4; ++kd)
    qf[kd] = *(const bf16x8*)&qp[(size_t)(qrow0 + l31) * HDD + kd * 16 + hi * 8];

  f32x16 O[2];
#pragma unroll
  for (int dt = 0; dt < 2; ++dt)
#pragma unroll
    for (int r = 0; r < 16; ++r) O[dt][r] = 0.f;
  float m2 = -1e30f, lsum = 0.f;

  const uint32_t vbase = lds_b(Vsm);
  int vwoff[NSTG];
  {
    int key0 = tid >> 3, dc = tid & 7;
#pragma unroll
    for (int u = 0; u < NSTG; ++u) {
      int key = u * 32 + key0;
      vwoff[u] = (((key >> 2) << 8) | ((dc >> 1) << 6) | ((key & 3) << 4) | ((dc & 1) << 3));
    }
  }

#define KB_OF(ci) ((ci) < 2 && MODE == 0 ? (ci) * 64 : (MODE == 0 ? bstart + ((ci) - 2) * 64 : ((split * 4 + (ci)) * 64)))

  // prologue: stage chunk 0 into buf 0
  bf16x8 vv[NSTG];
  {
    int kb = KB_OF(0);
#pragma unroll
    for (int u = 0; u < NSTG; ++u) {
      async16(&Ksm[0][(u * NW + w) * 512],
              kp + (size_t)(kb + (u * NW + w) * 8 + l3) * HDD + ((l7 ^ l3) << 3));
      vv[u] = *(const bf16x8*)&vp[(size_t)(kb + u * 32 + (tid >> 3)) * HDD + ((tid & 7) << 3)];
    }
  }
  int buf = 0;

  for (int ci = 0; ci < nch; ++ci) {
    const int kbase = KB_OF(ci);
    asm volatile("s_waitcnt vmcnt(0)" ::: "memory");  // K(ci) in LDS, V(ci) in regs
#pragma unroll
    for (int u = 0; u < NSTG; ++u) *(bf16x8*)&Vsm[buf][vwoff[u]] = vv[u];
    __syncthreads();

    if (ci + 1 < nch) {  // prefetch next chunk (hides under compute)
      int kb = KB_OF(ci + 1);
#pragma unroll
      for (int u = 0; u < NSTG; ++u) {
        async16(&Ksm[buf ^ 1][(u * NW + w) * 512],
                kp + (size_t)(kb + (u * NW + w) * 8 + l3) * HDD + ((l7 ^ l3) << 3));
        vv[u] = *(const bf16x8*)&vp[(size_t)(kb + u * 32 + (tid >> 3)) * HDD + ((tid & 7) << 3)];
      }
    }

    // ---- QK^T: sc[s] = K_sub(s) . Q^T, P[key][q], q = l31 per lane ----
    f32x16 sc[2];
#pragma unroll
    for (int s = 0; s < 2; ++s)
#pragma unroll
      for (int r = 0; r < 16; ++r) sc[s][r] = 0.f;
    __builtin_amdgcn_s_setprio(1);
#pragma unroll
    for (int kd = 0; kd < 4; ++kd) {
#pragma unroll
      for (int s = 0; s < 2; ++s) {
        int row = s * 32 + l31;
        bf16x8 kf = *(const bf16x8*)&Ksm[buf][row * 64 + ((((kd << 1) + hi) ^ (row & 7)) << 3)];
        sc[s] = __builtin_amdgcn_mfma_f32_32x32x16_bf16(kf, qf[kd], sc[s], 0, 0, 0);
      }
    }
    __builtin_amdgcn_s_setprio(0);

    // ---- band mask ----
    if (MODE == 0 && kbase >= GG) {
      const int base0 = (kbase - (n * 256 - 256)) - (w * 32 + l31);
#pragma unroll
      for (int s = 0; s < 2; ++s)
#pragma unroll
        for (int r = 0; r < 16; ++r) {
          int t = base0 + s * 32 + (r & 3) + 8 * (r >> 2) + 4 * hi;
          if ((unsigned)t > 512u) sc[s][r] = -1e9f;
        }
    }

    // ---- online softmax (per-lane q row; exp2 domain) ----
    float mh = sc[0][0];
#pragma unroll
    for (int s = 0; s < 2; ++s)
#pragma unroll
      for (int r = 0; r < 16; ++r) if (s || r) mh = fmaxf(mh, sc[s][r]);
    mh = fmaxf(mh, xhalf(mh, hi));
    float mnew = fmaxf(m2, mh * L2E);
    float alpha = exp2f(m2 - mnew);
    m2 = mnew;
    float sh = 0.f;
#pragma unroll
    for (int s = 0; s < 2; ++s)
#pragma unroll
      for (int r = 0; r < 16; ++r) {
        float pv = exp2f(__builtin_fmaf(sc[s][r], L2E, -mnew));
        sc[s][r] = pv;
        sh += pv;
      }
    sh += xhalf(sh, hi);
    lsum = lsum * alpha + sh;

    // ---- O rescale: alpha[q] broadcast (q per reg) ----
    if (l < 32) Alds[w][l] = alpha;
    f32x4 aT[4];
#pragma unroll
    for (int g2 = 0; g2 < 4; ++g2) aT[g2] = *(const f32x4*)&Alds[w][g2 * 8 + hi * 4];
#pragma unroll
    for (int dt = 0; dt < 2; ++dt)
#pragma unroll
      for (int r = 0; r < 16; ++r) O[dt][r] *= aT[r >> 2][r & 3];

    // ---- pack P -> A-fragments (cvt_pk + permlane32_swap, in-register) ----
    bf16x8 pa[4];
#pragma unroll
    for (int kk = 0; kk < 4; ++kk) {
      const int s = kk >> 1, h8 = (kk & 1) * 8;
      int x0 = (int)cvtpk(sc[s][h8 + 0], sc[s][h8 + 1]);
      int x1 = (int)cvtpk(sc[s][h8 + 2], sc[s][h8 + 3]);
      int y0 = (int)cvtpk(sc[s][h8 + 4], sc[s][h8 + 5]);
      int y1 = (int)cvtpk(sc[s][h8 + 6], sc[s][h8 + 7]);
      plswap(x0, y0); plswap(x1, y1);
      union { int u[4]; bf16x8 v; } pk;
      pk.u[0] = x0; pk.u[1] = x1; pk.u[2] = y0; pk.u[3] = y1;
      pa[kk] = pk.v;
    }

    // ---- PV: O[dt] += P . V ----
    const uint32_t vb = vbase + (uint32_t)(buf << 13);
#pragma unroll
    for (int dt = 0; dt < 2; ++dt) {
      s16x4 t0[4], t1[4];
#pragma unroll
      for (int kk = 0; kk < 4; ++kk) {
        int kg = kk * 4 + hi * 2;
        int dgrp = dt * 2 + (l31 >> 4);
        uint32_t a = vb + (uint32_t)((kg * 256 + dgrp * 64 + (l31 & 15)) << 1);
        t0[kk] = tr_read(a);
        t1[kk] = tr_read(a + 512);
      }
      asm volatile("s_waitcnt lgkmcnt(0)" ::: "memory");
      __builtin_amdgcn_sched_barrier(0);
      __builtin_amdgcn_s_setprio(1);
#pragma unroll
      for (int kk = 0; kk < 4; ++kk) {
        bf16x8 vf = __builtin_shufflevector(t0[kk], t1[kk], 0, 1, 2, 3, 4, 5, 6, 7);
        O[dt] = __builtin_amdgcn_mfma_f32_32x32x16_bf16(pa[kk], vf, O[dt], 0, 0, 0);
      }
      __builtin_amdgcn_s_setprio(0);
    }

    buf ^= 1;
  }

  // ---- epilogue ----
  if (MODE == 0) {
    if (l < 32) Alds[w][l] = 1.f / lsum;
    f32x4 iT[4];
#pragma unroll
    for (int g2 = 0; g2 < 4; ++g2) iT[g2] = *(const f32x4*)&Alds[w][g2 * 8 + hi * 4];
#pragma unroll
    for (int dt = 0; dt < 2; ++dt)
#pragma unroll
      for (int r = 0; r < 16; ++r) {
        int q = qrow0 + (r & 3) + 8 * (r >> 2) + 4 * hi;
        int d = dt * 32 + l31;
        ctx[((size_t)b * SS + q) * DD + h * HDD + d] = f2bf(O[dt][r] * iT[r >> 2][r & 3]);
      }
  } else {
    size_t pb = (bh * NSPLIT + split) * (size_t)GG;
#pragma unroll
    for (int dt = 0; dt < 2; ++dt)
#pragma unroll
      for (int r = 0; r < 16; ++r) {
        int q = w * 32 + (r & 3) + 8 * (r >> 2) + 4 * hi;
        Opart[(pb + q) * HDD + dt * 32 + l31] = O[dt][r];
      }
    if (l < 32) {
      size_t mb = (pb + w * 32 + l) * 2;
      mlp[mb] = m2;
      mlp[mb + 1] = lsum;
    }
  }
#undef KB_OF
}

// ---------------- split-K reduce for global queries (m in exp2 domain) ----------------
__global__ __launch_bounds__(256) void k_red(const float* __restrict__ Opart,
                                             const float* __restrict__ mlp,
                                             unsigned short* __restrict__ ctx) {
  int wid = blockIdx.x * 4 + (threadIdx.x >> 6);  // 0..3071 = bh*128 + q
  int d = threadIdx.x & 63;
  int bh = wid >> 7, q = wid & 127;
  int b = bh / HH, h = bh % HH;

  float mmax = -1e30f;
#pragma unroll
  for (int s = 0; s < NSPLIT; ++s)
    mmax = fmaxf(mmax, mlp[(((size_t)bh * NSPLIT + s) * GG + q) * 2]);
  float acc = 0.f, denom = 0.f;
#pragma unroll
  for (int s = 0; s < NSPLIT; ++s) {
    size_t mb = (((size_t)bh * NSPLIT + s) * GG + q) * 2;
    float wgt = exp2f(mlp[mb] - mmax);
    denom += wgt * mlp[mb + 1];
    acc += wgt * Opart[(((size_t)bh * NSPLIT + s) * GG + q) * HDD + d];
  }
  ctx[((size_t)b * SS + q) * DD + h * HDD + d] = f2bf(acc / denom);
}

// ---------------- layernorm ----------------
__global__ __launch_bounds__(256) void k_ln(const float* __restrict__ Y,
                                            const float* __restrict__ gam,
                                            const float* __restrict__ bet,
                                            float* __restrict__ outp) {
  const int row = blockIdx.x;
  const float* y = Y + (size_t)row * DD;
  float v0 = y[threadIdx.x], v1 = y[threadIdx.x + 256], v2 = y[threadIdx.x + 512];
  float s = v0 + v1 + v2, s2 = v0 * v0 + v1 * v1 + v2 * v2;
#pragma unroll
  for (int d = 1; d < 64; d <<= 1) { s += __shfl_xor(s, d, 64); s2 += __shfl_xor(s2, d, 64); }
  __shared__ float r1[4], r2[4];
  int w = threadIdx.x >> 6, l = threadIdx.x & 63;
  if (l == 0) { r1[w] = s; r2[w] = s2; }
  __syncthreads();
  s = r1[0] + r1[1] + r1[2] + r1[3];
  s2 = r2[0] + r2[1] + r2[2] + r2[3];
  float mu = s * (1.f / 768.f);
  float var = s2 * (1.f / 768.f) - mu * mu;
  float rstd = rsqrtf(var + 1e-5f);
  float* op = outp + (size_t)row * DD;
  op[threadIdx.x] = (v0 - mu) * rstd * gam[threadIdx.x] + bet[threadIdx.x];
  op[threadIdx.x + 256] = (v1 - mu) * rstd * gam[threadIdx.x + 256] + bet[threadIdx.x + 256];
  op[threadIdx.x + 512] = (v2 - mu) * rstd * gam[threadIdx.x + 512] + bet[threadIdx.x + 512];
}

// ---------------- launch ----------------
extern "C" void kernel_launch(void* const* d_in, const int* in_sizes, int n_in,
                              void* d_out, int out_size, void* d_ws, size_t ws_size,
                              hipStream_t stream) {
  const float* hidden = (const float*)d_in[0];
  const float* Wq = (const float*)d_in[3];  const float* bq = (const float*)d_in[4];
  const float* Wk = (const float*)d_in[5];  const float* bk = (const float*)d_in[6];
  const float* Wv = (const float*)d_in[7];  const float* bv = (const float*)d_in[8];
  const float* Wqg = (const float*)d_in[9]; const float* bqg = (const float*)d_in[10];
  const float* Wkg = (const float*)d_in[11]; const float* bkg = (const float*)d_in[12];
  const float* Wvg = (const float*)d_in[13]; const float* bvg = (const float*)d_in[14];
  const float* Wo = (const float*)d_in[15]; const float* bo = (const float*)d_in[16];
  const float* gam = (const float*)d_in[17]; const float* bet = (const float*)d_in[18];

  char* ws = (char*)d_ws;
  const size_t SZH = (size_t)BB * HH * SS * HDD;  // 6,291,456 elems per proj
  unsigned short* xb = (unsigned short*)(ws);                                   // 12.58 MB; later: ctx
  unsigned short* Wt5 = (unsigned short*)(ws + 12582912);                       // 5.90 MB
  unsigned short* Wtqg = (unsigned short*)(ws + 12582912 + 5898240);            // 1.18 MB
  unsigned short* Wto = (unsigned short*)(ws + 12582912 + 5898240 + 1179648);   // 1.18 MB
  unsigned short* qkv = (unsigned short*)(ws + 20840448);                       // 5 x 12.58 MB
  unsigned short* qg = (unsigned short*)(ws + 20840448 + 62914560);             // 0.39 MB
  float* Opart = (float*)(ws + 84148224);                                       // 12.58 MB
  float* mlp = (float*)(ws + 84148224 + 12582912);                              // 0.39 MB
  unsigned short* ctx = xb;      // alias: xb dead after qg GEMM
  float* Y = (float*)qkv;        // alias: q/k slots dead after attention

  k_cvt<<<dim3((BB * SS * DD / 4 + 255) / 256), dim3(256), 0, stream>>>(hidden, xb, BB * SS * DD / 4);

  WArgs wa;
  wa.s[0] = Wq; wa.s[1] = Wk; wa.s[2] = Wv; wa.s[3] = Wkg; wa.s[4] = Wvg; wa.s[5] = Wqg; wa.s[6] = Wo;
  wa.d[0] = Wt5; wa.d[1] = Wt5 + 589824; wa.d[2] = Wt5 + 2 * 589824;
  wa.d[3] = Wt5 + 3 * 589824; wa.d[4] = Wt5 + 4 * 589824;
  wa.d[5] = Wtqg; wa.d[6] = Wto;
  k_tw<<<dim3(12, 12, 7), dim3(256), 0, stream>>>(wa);

  k_gemm256<0><<<dim3(480), dim3(512), 0, stream>>>(xb, Wt5, bq, bk, bv, bkg, bvg, qkv, nullptr, nullptr);
  k_gemm<1><<<dim3(2, 6), dim3(256), 0, stream>>>(xb, Wtqg, bqg, nullptr, nullptr, nullptr, nullptr, qg, nullptr, nullptr);

  // global-query attention: split-K partials, then band attention, then reduce
  k_attn<1><<<dim3(BB * HH * NSPLIT), dim3(256), 0, stream>>>(qg, qkv + 3 * SZH, qkv + 4 * SZH,
                                                              nullptr, Opart, mlp);
  k_attn<0><<<dim3(BB * HH * NBB), dim3(512), 0, stream>>>(qkv, qkv + SZH, qkv + 2 * SZH,
                                                           ctx, nullptr, nullptr);
  k_red<<<dim3(BB * HH * GG / 4), dim3(256), 0, stream>>>(Opart, mlp, ctx);

  k_gemm<2><<<dim3(64, 6), dim3(256), 0, stream>>>(ctx, Wto, bo, nullptr, nullptr, nullptr, nullptr, nullptr, Y, hidden);

  k_ln<<<dim3(BB * SS), dim3(256), 0, stream>>>(Y, gam, bet, (float*)d_out);
}